// Round 4
// baseline (1890.983 us; speedup 1.0000x reference)
//
#include <hip/hip_runtime.h>

#define EPS   1e-8f
#define LAMB  20.0f
#define NI    128
#define NR    48
#define NT    64
#define NW    100
#define ND    768

typedef unsigned int uint;
typedef unsigned short ushortt;
typedef __attribute__((ext_vector_type(8))) short short8;
typedef __attribute__((ext_vector_type(4))) float f32x4;

// ======================= ws layout (fast path) ===========================
// floats: [0,6144) invQ, [6144,12544) invK, [12544,18688) nVi, [18688,25088) nVt
#define OFF_KHI  102400ULL                 // bf16 [64][128][768] (w>=100 zero)
#define OFF_KLO  12685312ULL
#define OFF_QHI  25268224ULL               // bf16 [128][48][768]
#define OFF_QLO  34705408ULL
#define OFF_TVT  44142592ULL               // bf16 [64][768][128] (w>=100 zero)
#define OFF_IVT  56725504ULL               // bf16 [128][768][64] (r>=48 zero)
#define WS_NEED  69308416ULL

__device__ inline unsigned short f2bf(float f) {
    uint u = __float_as_uint(f);
    u = (u + 0x7fffu + ((u >> 16) & 1u)) >> 16;
    return (unsigned short)u;
}
__device__ inline float bf2f(unsigned short h) {
    return __uint_as_float((uint)h << 16);
}
__device__ inline float wredsum(float v) {
#pragma unroll
    for (int m = 1; m < 64; m <<= 1) v += __shfl_xor(v, m, 64);
    return v;
}
__device__ inline float wredmax(float v) {
#pragma unroll
    for (int m = 1; m < 64; m <<= 1) v = fmaxf(v, __shfl_xor(v, m, 64));
    return v;
}
__device__ inline void split_store(float4 v, ushortt* hp, ushortt* lp) {
    unsigned short h0 = f2bf(v.x), h1 = f2bf(v.y), h2 = f2bf(v.z), h3 = f2bf(v.w);
    float f0 = bf2f(h0), f1 = bf2f(h1), f2 = bf2f(h2), f3 = bf2f(h3);
    ushort4 H; H.x = h0; H.y = h1; H.z = h2; H.w = h3;
    ushort4 L2; L2.x = f2bf(v.x - f0); L2.y = f2bf(v.y - f1); L2.z = f2bf(v.z - f2); L2.w = f2bf(v.w - f3);
    *(ushort4*)hp = H;
    *(ushort4*)lp = L2;
}

// ======================= prep kernels ====================================
__global__ void nafs_norms(const float* __restrict__ imgQ,
                           const float* __restrict__ imgV,
                           const float* __restrict__ txtK,
                           const float* __restrict__ txtV,
                           float* __restrict__ ws) {
    int row  = blockIdx.x * 4 + (threadIdx.x >> 6);
    int lane = threadIdx.x & 63;
    const float* src;
    int inv;
    if (row < 6144)       { src = imgQ + (size_t)row * ND;           inv = 1; }
    else if (row < 12544) { src = txtK + (size_t)(row - 6144) * ND;  inv = 1; }
    else if (row < 18688) { src = imgV + (size_t)(row - 12544) * ND; inv = 0; }
    else                  { src = txtV + (size_t)(row - 18688) * ND; inv = 0; }
    float ss = 0.f;
#pragma unroll
    for (int j = 0; j < 3; ++j) {
        float4 v = *(const float4*)(src + j * 256 + lane * 4);
        ss += v.x * v.x + v.y * v.y + v.z * v.z + v.w * v.w;
    }
#pragma unroll
    for (int off = 32; off > 0; off >>= 1) ss += __shfl_down(ss, off, 64);
    if (lane == 0) {
        float n = sqrtf(ss);
        ws[row] = inv ? (1.0f / (n + EPS)) : n;
    }
}

__global__ void nafs_convert(const float* __restrict__ txtK,
                             const float* __restrict__ imgQ,
                             const float* __restrict__ ws,
                             ushortt* __restrict__ khi, ushortt* __restrict__ klo,
                             ushortt* __restrict__ qhi, ushortt* __restrict__ qlo) {
    int row = blockIdx.x;
    int c4  = threadIdx.x;
    if (c4 >= 192) return;
    if (row < 8192) {
        int t = row >> 7, w = row & 127;
        size_t o = (size_t)row * ND + c4 * 4;
        if (w < NW) {
            float s = ws[6144 + t * NW + w];
            float4 v = *(const float4*)&txtK[((size_t)t * NW + w) * ND + c4 * 4];
            v.x *= s; v.y *= s; v.z *= s; v.w *= s;
            split_store(v, &khi[o], &klo[o]);
        } else {
            ushort4 z; z.x = z.y = z.z = z.w = 0;
            *(ushort4*)&khi[o] = z; *(ushort4*)&klo[o] = z;
        }
    } else {
        int q = row - 8192;
        float s = ws[q];
        float4 v = *(const float4*)&imgQ[(size_t)q * ND + c4 * 4];
        v.x *= s; v.y *= s; v.z *= s; v.w *= s;
        size_t o = (size_t)q * ND + c4 * 4;
        split_store(v, &qhi[o], &qlo[o]);
    }
}

__global__ void nafs_ttv(const float* __restrict__ txtV, ushortt* __restrict__ tvt) {
    __shared__ float sT[128 * 33];
    int t = blockIdx.x / 24, dt = blockIdx.x % 24, d0 = dt * 32;
    int tid = threadIdx.x;
    for (int idx = tid; idx < 128 * 8; idx += 256) {
        int w = idx >> 3, c4 = idx & 7;
        float4 v;
        if (w < NW) v = *(const float4*)&txtV[((size_t)t * NW + w) * ND + d0 + c4 * 4];
        else { v.x = v.y = v.z = v.w = 0.f; }
        float* p = &sT[w * 33 + c4 * 4];
        p[0] = v.x; p[1] = v.y; p[2] = v.z; p[3] = v.w;
    }
    __syncthreads();
    for (int idx = tid; idx < 32 * 32; idx += 256) {
        int w4 = idx & 31, c = idx >> 5;
        ushort4 o;
        o.x = f2bf(sT[(w4 * 4 + 0) * 33 + c]);
        o.y = f2bf(sT[(w4 * 4 + 1) * 33 + c]);
        o.z = f2bf(sT[(w4 * 4 + 2) * 33 + c]);
        o.w = f2bf(sT[(w4 * 4 + 3) * 33 + c]);
        *(ushort4*)&tvt[((size_t)t * ND + d0 + c) * 128 + w4 * 4] = o;
    }
}

__global__ void nafs_tiv(const float* __restrict__ imgV, ushortt* __restrict__ ivt) {
    __shared__ float sT[64 * 33];
    int i = blockIdx.x / 24, dt = blockIdx.x % 24, d0 = dt * 32;
    int tid = threadIdx.x;
    for (int idx = tid; idx < 64 * 8; idx += 256) {
        int r = idx >> 3, c4 = idx & 7;
        float4 v;
        if (r < NR) v = *(const float4*)&imgV[((size_t)i * NR + r) * ND + d0 + c4 * 4];
        else { v.x = v.y = v.z = v.w = 0.f; }
        float* p = &sT[r * 33 + c4 * 4];
        p[0] = v.x; p[1] = v.y; p[2] = v.z; p[3] = v.w;
    }
    __syncthreads();
    for (int idx = tid; idx < 16 * 32; idx += 256) {
        int r4 = idx & 15, c = idx >> 4;
        ushort4 o;
        o.x = f2bf(sT[(r4 * 4 + 0) * 33 + c]);
        o.y = f2bf(sT[(r4 * 4 + 1) * 33 + c]);
        o.z = f2bf(sT[(r4 * 4 + 2) * 33 + c]);
        o.w = f2bf(sT[(r4 * 4 + 3) * 33 + c]);
        *(ushort4*)&ivt[((size_t)i * ND + d0 + c) * 64 + r4 * 4] = o;
    }
}

// ======================= fused kernel (fast path) ========================
// LDS diet: shATT2 aliases dead aT region -> 36.4 KB -> 4 blocks/CU.
__global__ __launch_bounds__(256, 4)
void nafs_fused2(const float* __restrict__ imgV,
                 const int*  __restrict__ tlen,
                 const float* __restrict__ ws,
                 const ushortt* __restrict__ khi, const ushortt* __restrict__ klo,
                 const ushortt* __restrict__ qhi, const ushortt* __restrict__ qlo,
                 const ushortt* __restrict__ tvt, const ushortt* __restrict__ ivt,
                 float* __restrict__ out) {
    __shared__ __align__(16) float   aT[112 * 49];      // leaky(sim) fp32; later aliased by shATT2
    __shared__ __align__(16) ushortt shATT[48 * 128];   // attn bf16, XOR-swizzled blocks
    __shared__ float sInvW[NW], sInv2[NR], sCos1[NR], sCos2[112], sSS2[112], sDD2[112];
    ushortt* const shATT2 = (ushortt*)aT;               // attn2 bf16 [112][64], alias

    const int tid  = threadIdx.x;
    const int wv   = tid >> 6;
    const int lane = tid & 63;
    const int quad = lane >> 4;
    const int l15  = lane & 15;
    const int key  = l15 & 7;
    const int b    = blockIdx.x;
    const int t    = b >> 7;
    const int i    = b & 127;
    const int L    = tlen[t];
    const float Lf = (float)L;

    const float* __restrict__ nVi = ws + 12544;
    const float* __restrict__ nVt = ws + 18688;

    if (tid < 112) { sSS2[tid] = 0.f; sDD2[tid] = 0.f; }

    // ---------------- Phase 1: sim via 3-pass split bf16 MFMA ------------
    const int m0 = wv, m1 = wv + 4;
    const ushortt* pK0h = khi + ((size_t)t * 128 + m0 * 16 + l15) * ND + quad * 8;
    const ushortt* pK0l = klo + ((size_t)t * 128 + m0 * 16 + l15) * ND + quad * 8;
    const ushortt* pK1h = khi + ((size_t)t * 128 + m1 * 16 + l15) * ND + quad * 8;
    const ushortt* pK1l = klo + ((size_t)t * 128 + m1 * 16 + l15) * ND + quad * 8;
    const ushortt* pQh  = qhi + ((size_t)i * NR + l15) * ND + quad * 8;
    const ushortt* pQl  = qlo + ((size_t)i * NR + l15) * ND + quad * 8;

    f32x4 acc[2][3];
#pragma unroll
    for (int a = 0; a < 2; ++a)
#pragma unroll
        for (int n = 0; n < 3; ++n) acc[a][n] = (f32x4){0.f, 0.f, 0.f, 0.f};

    short8 cA0h, cA0l, cA1h, cA1l, cB0h, cB0l, cB1h, cB1l, cB2h, cB2l;
    cA0h = *(const short8*)(pK0h); cA0l = *(const short8*)(pK0l);
    cA1h = *(const short8*)(pK1h); cA1l = *(const short8*)(pK1l);
    cB0h = *(const short8*)(pQh);            cB0l = *(const short8*)(pQl);
    cB1h = *(const short8*)(pQh + 16 * ND);  cB1l = *(const short8*)(pQl + 16 * ND);
    cB2h = *(const short8*)(pQh + 32 * ND);  cB2l = *(const short8*)(pQl + 32 * ND);

    for (int dc = 0; dc < ND; dc += 32) {
        short8 nA0h, nA0l, nA1h, nA1l, nB0h, nB0l, nB1h, nB1l, nB2h, nB2l;
        int dn = dc + 32;
        if (dn < ND) {
            nA0h = *(const short8*)(pK0h + dn); nA0l = *(const short8*)(pK0l + dn);
            nA1h = *(const short8*)(pK1h + dn); nA1l = *(const short8*)(pK1l + dn);
            nB0h = *(const short8*)(pQh + dn);           nB0l = *(const short8*)(pQl + dn);
            nB1h = *(const short8*)(pQh + 16 * ND + dn); nB1l = *(const short8*)(pQl + 16 * ND + dn);
            nB2h = *(const short8*)(pQh + 32 * ND + dn); nB2l = *(const short8*)(pQl + 32 * ND + dn);
        }
        acc[0][0] = __builtin_amdgcn_mfma_f32_16x16x32_bf16(cA0h, cB0h, acc[0][0], 0, 0, 0);
        acc[0][0] = __builtin_amdgcn_mfma_f32_16x16x32_bf16(cA0h, cB0l, acc[0][0], 0, 0, 0);
        acc[0][0] = __builtin_amdgcn_mfma_f32_16x16x32_bf16(cA0l, cB0h, acc[0][0], 0, 0, 0);
        acc[0][1] = __builtin_amdgcn_mfma_f32_16x16x32_bf16(cA0h, cB1h, acc[0][1], 0, 0, 0);
        acc[0][1] = __builtin_amdgcn_mfma_f32_16x16x32_bf16(cA0h, cB1l, acc[0][1], 0, 0, 0);
        acc[0][1] = __builtin_amdgcn_mfma_f32_16x16x32_bf16(cA0l, cB1h, acc[0][1], 0, 0, 0);
        acc[0][2] = __builtin_amdgcn_mfma_f32_16x16x32_bf16(cA0h, cB2h, acc[0][2], 0, 0, 0);
        acc[0][2] = __builtin_amdgcn_mfma_f32_16x16x32_bf16(cA0h, cB2l, acc[0][2], 0, 0, 0);
        acc[0][2] = __builtin_amdgcn_mfma_f32_16x16x32_bf16(cA0l, cB2h, acc[0][2], 0, 0, 0);
        acc[1][0] = __builtin_amdgcn_mfma_f32_16x16x32_bf16(cA1h, cB0h, acc[1][0], 0, 0, 0);
        acc[1][0] = __builtin_amdgcn_mfma_f32_16x16x32_bf16(cA1h, cB0l, acc[1][0], 0, 0, 0);
        acc[1][0] = __builtin_amdgcn_mfma_f32_16x16x32_bf16(cA1l, cB0h, acc[1][0], 0, 0, 0);
        acc[1][1] = __builtin_amdgcn_mfma_f32_16x16x32_bf16(cA1h, cB1h, acc[1][1], 0, 0, 0);
        acc[1][1] = __builtin_amdgcn_mfma_f32_16x16x32_bf16(cA1h, cB1l, acc[1][1], 0, 0, 0);
        acc[1][1] = __builtin_amdgcn_mfma_f32_16x16x32_bf16(cA1l, cB1h, acc[1][1], 0, 0, 0);
        acc[1][2] = __builtin_amdgcn_mfma_f32_16x16x32_bf16(cA1h, cB2h, acc[1][2], 0, 0, 0);
        acc[1][2] = __builtin_amdgcn_mfma_f32_16x16x32_bf16(cA1h, cB2l, acc[1][2], 0, 0, 0);
        acc[1][2] = __builtin_amdgcn_mfma_f32_16x16x32_bf16(cA1l, cB2h, acc[1][2], 0, 0, 0);
        if (dn < ND) {
            cA0h = nA0h; cA0l = nA0l; cA1h = nA1h; cA1l = nA1l;
            cB0h = nB0h; cB0l = nB0l; cB1h = nB1h; cB1l = nB1l; cB2h = nB2h; cB2l = nB2l;
        }
    }
#pragma unroll
    for (int a = 0; a < 2; ++a) {
        int m = (a == 0) ? m0 : m1;
        if (m < 7) {
#pragma unroll
            for (int n = 0; n < 3; ++n) {
#pragma unroll
                for (int reg = 0; reg < 4; ++reg) {
                    float s = acc[a][n][reg];
                    aT[(m * 16 + quad * 4 + reg) * 49 + n * 16 + l15] = (s > 0.f) ? s : 0.1f * s;
                }
            }
        }
    }
    __syncthreads();

    // ---------------- Phase 2: norms + both attentions -------------------
    if (tid < NW) {
        float ssum = 0.f;
#pragma unroll 8
        for (int r = 0; r < NR; ++r) { float v = aT[tid * 49 + r]; ssum += v * v; }
        sInvW[tid] = 1.0f / (sqrtf(ssum) + EPS);
    } else if (tid >= 128 && tid < 128 + NR) {
        int r = tid - 128;
        float ssum = 0.f;
        for (int w = 0; w < L; ++w) { float v = aT[w * 49 + r]; ssum += v * v; }
        sInv2[r] = 1.0f / (sqrtf(ssum) + EPS);
    }
    __syncthreads();

    // branch-1 attn: writes shATT (separate region) while aT still live
    for (int r = wv; r < NR; r += 4) {
        int w1 = lane, w2 = lane + 64;
        int v1ok = (w1 < L), v2ok = (w2 < L);
        float v1 = v1ok ? aT[w1 * 49 + r] * sInvW[w1] * LAMB : -1e30f;
        float v2 = v2ok ? aT[w2 * 49 + r] * sInvW[w2] * LAMB : -1e30f;
        float m  = wredmax(fmaxf(v1, v2));
        float e1 = v1ok ? expf(v1 - m) : 0.f;
        float e2 = v2ok ? expf(v2 - m) : 0.f;
        float inv = 1.0f / wredsum(e1 + e2);
        float p1 = e1 * inv, p2 = e2 * inv;
        float S1 = wredsum(p1 + p2);
        float t1 = ((p1 * Lf - S1) > 0.f) ? p1 : 0.f;
        float t2 = ((p2 * Lf - S1) > 0.f) ? p2 : 0.f;
        float S2 = wredsum(t1 + t2);
        float iS2 = 1.0f / ((S2 > 0.f) ? S2 : 1.0f);
        shATT[r * 128 + (((w1 >> 3) ^ (r & 7)) << 3) + (w1 & 7)] = f2bf(t1 * iS2);
        shATT[r * 128 + (((w2 >> 3) ^ (r & 7)) << 3) + (w2 & 7)] = f2bf(t2 * iS2);
    }
    // branch-2 attn2: reads aT, stages values in REGISTERS (shATT2 aliases aT)
    float s2v[28];
#pragma unroll
    for (int k = 0; k < 28; ++k) {
        int w = wv + 4 * k;
        float val = 0.f;
        if (w < L) {
            int rok = (lane < NR);
            float v = rok ? aT[w * 49 + lane] * sInv2[lane] * LAMB : -1e30f;
            float m = wredmax(v);
            float e = rok ? expf(v - m) : 0.f;
            float inv = 1.0f / wredsum(e);
            float p = e * inv;
            float S1 = wredsum(p);
            float tm = ((p * 48.0f - S1) > 0.f) ? p : 0.f;
            float S2 = wredsum(tm);
            float iS2 = 1.0f / ((S2 > 0.f) ? S2 : 1.0f);
            val = tm * iS2;
        }
        s2v[k] = val;
    }
    __syncthreads();             // all aT reads complete chip... block-wide
#pragma unroll
    for (int k = 0; k < 28; ++k) {
        int w = wv + 4 * k;
        shATT2[w * 64 + (((lane >> 3) ^ (w & 7)) << 3) + (lane & 7)] = f2bf(s2v[k]);
    }
    __syncthreads();

    // ---------------- B1: weiText cosine (waves 0-2, pipelined) ----------
    const int ntot = (L + 15) >> 4;
    if (wv < 3) {
        float ss1[4] = {0.f, 0.f, 0.f, 0.f}, dd1[4] = {0.f, 0.f, 0.f, 0.f};
        const ushortt* attRow = &shATT[(wv * 16 + l15) * 128];
        const ushortt* tvcB   = &tvt[((size_t)t * ND + l15) * 128 + quad * 8];
        const float*   ivB0   = &imgV[((size_t)i * NR + wv * 16 + quad * 4) * ND + l15];
        short8 af[4];
#pragma unroll
        for (int ks = 0; ks < 4; ++ks)        // loop-invariant: attn fragment
            af[ks] = *(const short8*)&attRow[(((ks * 4 + quad) ^ key)) << 3];
        short8 tA[4]; float vA[4];
#pragma unroll
        for (int ks = 0; ks < 4; ++ks) tA[ks] = *(const short8*)&tvcB[(size_t)ks * 32];
#pragma unroll
        for (int reg = 0; reg < 4; ++reg) vA[reg] = ivB0[reg * ND];
        for (int s = 0; s < 48; ++s) {        // s = cc*2+n, d-offset = s*16
            short8 tN[4]; float vN[4];
            if (s < 47) {
                size_t d0 = (size_t)(s + 1) * 16;
#pragma unroll
                for (int ks = 0; ks < 4; ++ks)
                    tN[ks] = *(const short8*)&tvcB[d0 * 128 + ks * 32];
#pragma unroll
                for (int reg = 0; reg < 4; ++reg)
                    vN[reg] = ivB0[reg * ND + d0];
            }
            f32x4 u = (f32x4){0.f, 0.f, 0.f, 0.f};
#pragma unroll
            for (int ks = 0; ks < 4; ++ks)
                u = __builtin_amdgcn_mfma_f32_16x16x32_bf16(af[ks], tA[ks], u, 0, 0, 0);
#pragma unroll
            for (int reg = 0; reg < 4; ++reg) {
                float uu = u[reg];
                ss1[reg] = fmaf(uu, uu, ss1[reg]);
                dd1[reg] = fmaf(uu, vA[reg], dd1[reg]);
            }
            if (s < 47) {
#pragma unroll
                for (int q2 = 0; q2 < 4; ++q2) { tA[q2] = tN[q2]; vA[q2] = vN[q2]; }
            }
        }
#pragma unroll
        for (int reg = 0; reg < 4; ++reg) {
            float s = ss1[reg], d = dd1[reg];
#pragma unroll
            for (int m = 1; m < 16; m <<= 1) { s += __shfl_xor(s, m, 64); d += __shfl_xor(d, m, 64); }
            if (l15 == 0) {
                int r = wv * 16 + quad * 4 + reg;
                float nu  = sqrtf(s);
                float num = d / (nu + EPS);
                float den = fmaxf(nVi[i * NR + r] * (nu / (nu + EPS)), EPS);
                sCos1[r] = num / den;
            }
        }
    }

    // ---------------- B2: weiImage cosine (all waves, pipelined) ---------
    {
        const int ctb = (wv < 3) ? wv * 10 : 30;
        const int ctn = (wv < 3) ? 10 : 18;
        const ushortt* ivtB = &ivt[(size_t)i * ND * 64 + (size_t)l15 * 64 + quad * 8];
        const ushortt* tvpB = &tvt[((size_t)t * ND + quad * 4) * 128 + l15];
        for (int nt = 0; nt < ntot; ++nt) {
            const ushortt* a2row = &shATT2[(nt * 16 + l15) * 64];
            short8 b0 = *(const short8*)&a2row[((quad ^ key)) << 3];
            short8 b1 = *(const short8*)&a2row[(((4 + quad) ^ key)) << 3];
            float ss = 0.f, dd = 0.f;
            short8 aA0 = *(const short8*)&ivtB[(size_t)ctb * 1024];
            short8 aA1 = *(const short8*)&ivtB[(size_t)ctb * 1024 + 32];
            ushortt tvA[4];
#pragma unroll
            for (int reg = 0; reg < 4; ++reg)
                tvA[reg] = tvpB[(size_t)(ctb * 16 + reg) * 128 + nt * 16];
            for (int j = 0; j < ctn; ++j) {
                short8 aN0, aN1; ushortt tvN[4];
                if (j + 1 < ctn) {
                    int c1 = ctb + j + 1;
                    aN0 = *(const short8*)&ivtB[(size_t)c1 * 1024];
                    aN1 = *(const short8*)&ivtB[(size_t)c1 * 1024 + 32];
#pragma unroll
                    for (int reg = 0; reg < 4; ++reg)
                        tvN[reg] = tvpB[(size_t)(c1 * 16 + reg) * 128 + nt * 16];
                }
                f32x4 u = (f32x4){0.f, 0.f, 0.f, 0.f};
                u = __builtin_amdgcn_mfma_f32_16x16x32_bf16(aA0, b0, u, 0, 0, 0);
                u = __builtin_amdgcn_mfma_f32_16x16x32_bf16(aA1, b1, u, 0, 0, 0);
#pragma unroll
                for (int reg = 0; reg < 4; ++reg) {
                    float uu = u[reg];
                    ss = fmaf(uu, uu, ss);
                    dd = fmaf(uu, bf2f(tvA[reg]), dd);
                }
                if (j + 1 < ctn) {
                    aA0 = aN0; aA1 = aN1;
#pragma unroll
                    for (int reg = 0; reg < 4; ++reg) tvA[reg] = tvN[reg];
                }
            }
            ss += __shfl_xor(ss, 16, 64); dd += __shfl_xor(dd, 16, 64);
            ss += __shfl_xor(ss, 32, 64); dd += __shfl_xor(dd, 32, 64);
            if (quad == 0) {
                atomicAdd(&sSS2[nt * 16 + l15], ss);
                atomicAdd(&sDD2[nt * 16 + l15], dd);
            }
        }
    }
    __syncthreads();
    if (tid < 112 && tid < L) {
        float s = sSS2[tid], d = sDD2[tid];
        float nu  = sqrtf(s);
        float num = d / (nu + EPS);
        float den = fmaxf(nVt[t * NW + tid] * (nu / (nu + EPS)), EPS);
        sCos2[tid] = num / den;
    }
    __syncthreads();
    if (tid == 0) {
        float s = 0.f;
        for (int r = 0; r < NR; ++r) s += sCos1[r];
        out[i * NT + t] = s * (1.0f / 48.0f);
    } else if (tid == 64) {
        float s = 0.f;
        for (int w = 0; w < L; ++w) s += sCos2[w];
        out[NI * NT + i * NT + t] = s / Lf;
    }
}

// ======================= fallback (round-2 kernel) =======================
#define A_KH   0
#define A_KL   4480
#define A_QH   8960
#define A_QL   10880
#define A_ATT  0
#define A_ATT2 6528
#define SHA_SZ 14592
#define B1_TVT 3200
#define B2_IVT 6656
#define SHB_SZ 4900

__global__ __launch_bounds__(256, 3)
void nafs_fused_fb(const float* __restrict__ imgQ,
                   const float* __restrict__ imgV,
                   const float* __restrict__ txtK,
                   const float* __restrict__ txtV,
                   const int*  __restrict__ tlen,
                   const float* __restrict__ ws,
                   float* __restrict__ out) {
    __shared__ ushortt shA[SHA_SZ];
    __shared__ float shB[SHB_SZ];
    __shared__ float sKs[NW], sQs[NR], sInvW[NW], sInv2[NR], sCos1[NR], sCos2[112];

    const int tid  = threadIdx.x;
    const int wv   = tid >> 6;
    const int lane = tid & 63;
    const int quad = lane >> 4;
    const int l15  = lane & 15;
    const int b    = blockIdx.x;
    const int t    = b >> 7;
    const int i    = b & 127;
    const int L    = tlen[t];
    const float Lf = (float)L;

    const float* __restrict__ invQ = ws;
    const float* __restrict__ invK = ws + 6144;
    const float* __restrict__ nVi  = ws + 12544;
    const float* __restrict__ nVt  = ws + 18688;

    const float* Kbase  = txtK + (size_t)t * (NW * ND);
    const float* Qbase  = imgQ + (size_t)i * (NR * ND);
    const float* TVbase = txtV + (size_t)t * (NW * ND);
    const float* IVbase = imgV + (size_t)i * (NR * ND);

    if (tid < NW)                  sKs[tid]       = invK[t * NW + tid];
    else if (tid < NW + NR)        sQs[tid - NW]  = invQ[i * NR + (tid - NW)];

    const int mt0 = wv * 2, mt1 = wv * 2 + 1;
    f32x4 acc[2][3];
#pragma unroll
    for (int a = 0; a < 2; ++a)
#pragma unroll
        for (int n = 0; n < 3; ++n) acc[a][n] = (f32x4){0.f, 0.f, 0.f, 0.f};

    for (int dc = 0; dc < ND; dc += 32) {
        __syncthreads();
        for (int idx = tid; idx < 112 * 8; idx += 256) {
            int w = idx >> 3, seg = idx & 7;
            float4 v;
            if (w < NW) {
                v = *(const float4*)(Kbase + (size_t)w * ND + dc + seg * 4);
                float s = sKs[w];
                v.x *= s; v.y *= s; v.z *= s; v.w *= s;
            } else { v.x = v.y = v.z = v.w = 0.f; }
            split_store(v, &shA[A_KH + w * 40 + seg * 4], &shA[A_KL + w * 40 + seg * 4]);
        }
        for (int idx = tid; idx < NR * 8; idx += 256) {
            int r = idx >> 3, seg = idx & 7;
            float4 v = *(const float4*)(Qbase + (size_t)r * ND + dc + seg * 4);
            float s = sQs[r];
            v.x *= s; v.y *= s; v.z *= s; v.w *= s;
            split_store(v, &shA[A_QH + r * 40 + seg * 4], &shA[A_QL + r * 40 + seg * 4]);
        }
        __syncthreads();
        short8 bh[3], bl[3];
#pragma unroll
        for (int n = 0; n < 3; ++n) {
            bh[n] = *(const short8*)&shA[A_QH + (n * 16 + l15) * 40 + quad * 8];
            bl[n] = *(const short8*)&shA[A_QL + (n * 16 + l15) * 40 + quad * 8];
        }
#pragma unroll
        for (int a = 0; a < 2; ++a) {
            int m = (a == 0) ? mt0 : mt1;
            if (m < 7) {
                short8 ah = *(const short8*)&shA[A_KH + (m * 16 + l15) * 40 + quad * 8];
                short8 al = *(const short8*)&shA[A_KL + (m * 16 + l15) * 40 + quad * 8];
#pragma unroll
                for (int n = 0; n < 3; ++n) {
                    acc[a][n] = __builtin_amdgcn_mfma_f32_16x16x32_bf16(ah, bh[n], acc[a][n], 0, 0, 0);
                    acc[a][n] = __builtin_amdgcn_mfma_f32_16x16x32_bf16(ah, bl[n], acc[a][n], 0, 0, 0);
                    acc[a][n] = __builtin_amdgcn_mfma_f32_16x16x32_bf16(al, bh[n], acc[a][n], 0, 0, 0);
                }
            }
        }
    }
    __syncthreads();
#pragma unroll
    for (int a = 0; a < 2; ++a) {
        int m = (a == 0) ? mt0 : mt1;
        if (m < 7) {
#pragma unroll
            for (int n = 0; n < 3; ++n) {
#pragma unroll
                for (int reg = 0; reg < 4; ++reg) {
                    int w = m * 16 + quad * 4 + reg;
                    if (w < NW) {
                        float s = acc[a][n][reg];
                        shB[w * 49 + n * 16 + l15] = (s > 0.f) ? s : 0.1f * s;
                    }
                }
            }
        }
    }
    __syncthreads();

    if (tid < NW) {
        float ssum = 0.f;
#pragma unroll 8
        for (int r = 0; r < NR; ++r) { float v = shB[tid * 49 + r]; ssum += v * v; }
        sInvW[tid] = 1.0f / (sqrtf(ssum) + EPS);
    } else if (tid >= 128 && tid < 128 + NR) {
        int r = tid - 128;
        float ssum = 0.f;
        for (int w = 0; w < L; ++w) { float v = shB[w * 49 + r]; ssum += v * v; }
        sInv2[r] = 1.0f / (sqrtf(ssum) + EPS);
    }
    __syncthreads();

    for (int r = wv; r < NR; r += 4) {
        int w1 = lane, w2 = lane + 64;
        int v1ok = (w1 < L), v2ok = (w2 < L);
        float v1 = v1ok ? shB[w1 * 49 + r] * sInvW[w1] * LAMB : -1e30f;
        float v2 = v2ok ? shB[w2 * 49 + r] * sInvW[w2] * LAMB : -1e30f;
        float m  = wredmax(fmaxf(v1, v2));
        float e1 = v1ok ? expf(v1 - m) : 0.f;
        float e2 = v2ok ? expf(v2 - m) : 0.f;
        float inv = 1.0f / wredsum(e1 + e2);
        float p1 = e1 * inv, p2 = e2 * inv;
        float S1 = wredsum(p1 + p2);
        float t1 = ((p1 * Lf - S1) > 0.f) ? p1 : 0.f;
        float t2 = ((p2 * Lf - S1) > 0.f) ? p2 : 0.f;
        float S2 = wredsum(t1 + t2);
        float iS2 = 1.0f / ((S2 > 0.f) ? S2 : 1.0f);
        shA[A_ATT + r * 136 + w1] = f2bf(t1 * iS2);
        shA[A_ATT + r * 136 + w2] = f2bf(t2 * iS2);
    }
    for (int w = wv; w < L; w += 4) {
        int rok = (lane < NR);
        float v = rok ? shB[w * 49 + lane] * sInv2[lane] * LAMB : -1e30f;
        float m = wredmax(v);
        float e = rok ? expf(v - m) : 0.f;
        float inv = 1.0f / wredsum(e);
        float p = e * inv;
        float S1 = wredsum(p);
        float tm = ((p * 48.0f - S1) > 0.f) ? p : 0.f;
        float S2 = wredsum(tm);
        float iS2 = 1.0f / ((S2 > 0.f) ? S2 : 1.0f);
        shA[A_ATT2 + w * 72 + lane] = f2bf(tm * iS2);
    }
    for (int w = L + wv; w < 112; w += 4) shA[A_ATT2 + w * 72 + lane] = 0;
    __syncthreads();

    ushortt* shBu = (ushortt*)shB;
    const int kk = (L + 31) >> 5;
    float ss1[4] = {0.f, 0.f, 0.f, 0.f}, dd1[4] = {0.f, 0.f, 0.f, 0.f};
    const int mt = wv;
    const int cgrp = tid >> 5, ccol = tid & 31;

    for (int cc = 0; cc < ND; cc += 32) {
        __syncthreads();
        for (int w = cgrp; w < 128; w += 8) {
            float val = (w < NW) ? TVbase[(size_t)w * ND + cc + ccol] : 0.f;
            shBu[B1_TVT + ccol * 136 + w] = f2bf(val);
        }
        for (int idx = tid; idx < NR * 8; idx += 256) {
            int r = idx >> 3, seg = idx & 7;
            float4 v = *(const float4*)(IVbase + (size_t)r * ND + cc + seg * 4);
            float* p = &shB[r * 33 + seg * 4];
            p[0] = v.x; p[1] = v.y; p[2] = v.z; p[3] = v.w;
        }
        __syncthreads();
        if (mt < 3) {
            f32x4 u[2] = {(f32x4){0.f,0.f,0.f,0.f}, (f32x4){0.f,0.f,0.f,0.f}};
            for (int ks = 0; ks < kk; ++ks) {
                short8 a = *(const short8*)&shA[A_ATT + (mt * 16 + l15) * 136 + ks * 32 + quad * 8];
#pragma unroll
                for (int n = 0; n < 2; ++n) {
                    short8 bb = *(const short8*)&shBu[B1_TVT + (n * 16 + l15) * 136 + ks * 32 + quad * 8];
                    u[n] = __builtin_amdgcn_mfma_f32_16x16x32_bf16(a, bb, u[n], 0, 0, 0);
                }
            }
#pragma unroll
            for (int n = 0; n < 2; ++n) {
#pragma unroll
                for (int reg = 0; reg < 4; ++reg) {
                    int r = mt * 16 + quad * 4 + reg;
                    float uu = u[n][reg];
                    ss1[reg] = fmaf(uu, uu, ss1[reg]);
                    dd1[reg] = fmaf(uu, shB[r * 33 + n * 16 + l15], dd1[reg]);
                }
            }
        }
    }
    if (mt < 3) {
#pragma unroll
        for (int reg = 0; reg < 4; ++reg) {
            float s = ss1[reg], d = dd1[reg];
#pragma unroll
            for (int m = 1; m < 16; m <<= 1) { s += __shfl_xor(s, m, 64); d += __shfl_xor(d, m, 64); }
            if (l15 == 0) {
                int r = mt * 16 + quad * 4 + reg;
                float nu  = sqrtf(s);
                float num = d / (nu + EPS);
                float den = fmaxf(nVi[i * NR + r] * (nu / (nu + EPS)), EPS);
                sCos1[r] = num / den;
            }
        }
    }

    const int ntot = (L + 15) >> 4;
    float ss2[2] = {0.f, 0.f}, dd2[2] = {0.f, 0.f};

    for (int cc = 0; cc < ND; cc += 32) {
        __syncthreads();
        for (int idx = tid; idx < NW * 8; idx += 256) {
            int w = idx >> 3, seg = idx & 7;
            float4 v = *(const float4*)(TVbase + (size_t)w * ND + cc + seg * 4);
            float* p = &shB[w * 33 + seg * 4];
            p[0] = v.x; p[1] = v.y; p[2] = v.z; p[3] = v.w;
        }
        for (int r = cgrp; r < 64; r += 8) {
            float val = (r < NR) ? IVbase[(size_t)i * 0 + (size_t)r * ND + cc + ccol] : 0.f;
            shBu[B2_IVT + ccol * 72 + r] = f2bf(val);
        }
        __syncthreads();
#pragma unroll
        for (int pp = 0; pp < 2; ++pp) {
            int nt = wv + 4 * pp;
            if (nt < ntot) {
                f32x4 u[2] = {(f32x4){0.f,0.f,0.f,0.f}, (f32x4){0.f,0.f,0.f,0.f}};
#pragma unroll
                for (int ks = 0; ks < 2; ++ks) {
                    short8 bb = *(const short8*)&shA[A_ATT2 + (nt * 16 + l15) * 72 + ks * 32 + quad * 8];
#pragma unroll
                    for (int mm = 0; mm < 2; ++mm) {
                        short8 aa = *(const short8*)&shBu[B2_IVT + (mm * 16 + l15) * 72 + ks * 32 + quad * 8];
                        u[mm] = __builtin_amdgcn_mfma_f32_16x16x32_bf16(aa, bb, u[mm], 0, 0, 0);
                    }
                }
                int w = nt * 16 + l15;
                float tvok = (w < L) ? 1.f : 0.f;
#pragma unroll
                for (int mm = 0; mm < 2; ++mm) {
#pragma unroll
                    for (int reg = 0; reg < 4; ++reg) {
                        int c = mm * 16 + quad * 4 + reg;
                        float uu = u[mm][reg];
                        float tv = (w < L) ? shB[w * 33 + c] : 0.f;
                        ss2[pp] = fmaf(uu, uu, ss2[pp]);
                        dd2[pp] = fmaf(uu, tv * tvok, dd2[pp]);
                    }
                }
            }
        }
    }
#pragma unroll
    for (int pp = 0; pp < 2; ++pp) {
        int nt = wv + 4 * pp;
        if (nt < ntot) {
            float s = ss2[pp], d = dd2[pp];
            s += __shfl_xor(s, 16, 64); d += __shfl_xor(d, 16, 64);
            s += __shfl_xor(s, 32, 64); d += __shfl_xor(d, 32, 64);
            if (quad == 0) {
                int w = nt * 16 + l15;
                if (w < L) {
                    float nu  = sqrtf(s);
                    float num = d / (nu + EPS);
                    float den = fmaxf(nVt[t * NW + w] * (nu / (nu + EPS)), EPS);
                    sCos2[w] = num / den;
                }
            }
        }
    }
    __syncthreads();
    if (tid == 0) {
        float s = 0.f;
        for (int r = 0; r < NR; ++r) s += sCos1[r];
        out[i * NT + t] = s * (1.0f / 48.0f);
    } else if (tid == 64) {
        float s = 0.f;
        for (int w = 0; w < L; ++w) s += sCos2[w];
        out[NI * NT + i * NT + t] = s / Lf;
    }
}

extern "C" void kernel_launch(void* const* d_in, const int* in_sizes, int n_in,
                              void* d_out, int out_size, void* d_ws, size_t ws_size,
                              hipStream_t stream) {
    (void)in_sizes; (void)n_in; (void)out_size;
    const float* imgQ = (const float*)d_in[0];
    const float* imgV = (const float*)d_in[1];
    const float* txtK = (const float*)d_in[2];
    const float* txtV = (const float*)d_in[3];
    const int*   tlen = (const int*)d_in[4];
    float* ws  = (float*)d_ws;
    float* out = (float*)d_out;

    hipLaunchKernelGGL(nafs_norms, dim3(6272), dim3(256), 0, stream,
                       imgQ, imgV, txtK, txtV, ws);

    if (ws_size >= WS_NEED) {
        char* base = (char*)d_ws;
        ushortt* khi = (ushortt*)(base + OFF_KHI);
        ushortt* klo = (ushortt*)(base + OFF_KLO);
        ushortt* qhi = (ushortt*)(base + OFF_QHI);
        ushortt* qlo = (ushortt*)(base + OFF_QLO);
        ushortt* tvt = (ushortt*)(base + OFF_TVT);
        ushortt* ivt = (ushortt*)(base + OFF_IVT);
        hipLaunchKernelGGL(nafs_convert, dim3(14336), dim3(256), 0, stream,
                           txtK, imgQ, ws, khi, klo, qhi, qlo);
        hipLaunchKernelGGL(nafs_ttv, dim3(1536), dim3(256), 0, stream, txtV, tvt);
        hipLaunchKernelGGL(nafs_tiv, dim3(3072), dim3(256), 0, stream, imgV, ivt);
        hipLaunchKernelGGL(nafs_fused2, dim3(NT * NI), dim3(256), 0, stream,
                           imgV, tlen, ws, khi, klo, qhi, qlo, tvt, ivt, out);
    } else {
        hipLaunchKernelGGL(nafs_fused_fb, dim3(NT * NI), dim3(256), 0, stream,
                           imgQ, imgV, txtK, txtV, tlen, ws, out);
    }
}

// Round 5
// 1630.690 us; speedup vs baseline: 1.1596x; 1.1596x over previous
//
#include <hip/hip_runtime.h>

#define EPS   1e-8f
#define LAMB  20.0f
#define NI    128
#define NR    48
#define NT    64
#define NW    100
#define ND    768

typedef unsigned int uint;
typedef unsigned short ushortt;
typedef __attribute__((ext_vector_type(8))) short short8;
typedef __attribute__((ext_vector_type(4))) float f32x4;

// ======================= ws layout (fast path) ===========================
// floats: [0,6144) invQ, [6144,12544) invK, [12544,18688) nVi, [18688,25088) nVt
#define OFF_KHI  102400ULL                 // bf16 [64][128][768] (w>=100 zero)
#define OFF_KLO  12685312ULL
#define OFF_QHI  25268224ULL               // bf16 [128][48][768]
#define OFF_QLO  34705408ULL
#define OFF_TVT  44142592ULL               // bf16 [64][768][128] (w>=100 zero)
#define OFF_IVT  56725504ULL               // bf16 [128][768][64] (r>=48 zero)
#define WS_NEED  69308416ULL

__device__ inline unsigned short f2bf(float f) {
    uint u = __float_as_uint(f);
    u = (u + 0x7fffu + ((u >> 16) & 1u)) >> 16;
    return (unsigned short)u;
}
__device__ inline float bf2f(unsigned short h) {
    return __uint_as_float((uint)h << 16);
}
__device__ inline float wredsum(float v) {
#pragma unroll
    for (int m = 1; m < 64; m <<= 1) v += __shfl_xor(v, m, 64);
    return v;
}
__device__ inline float wredmax(float v) {
#pragma unroll
    for (int m = 1; m < 64; m <<= 1) v = fmaxf(v, __shfl_xor(v, m, 64));
    return v;
}
__device__ inline void split_store(float4 v, ushortt* hp, ushortt* lp) {
    unsigned short h0 = f2bf(v.x), h1 = f2bf(v.y), h2 = f2bf(v.z), h3 = f2bf(v.w);
    float f0 = bf2f(h0), f1 = bf2f(h1), f2 = bf2f(h2), f3 = bf2f(h3);
    ushort4 H; H.x = h0; H.y = h1; H.z = h2; H.w = h3;
    ushort4 L2; L2.x = f2bf(v.x - f0); L2.y = f2bf(v.y - f1); L2.z = f2bf(v.z - f2); L2.w = f2bf(v.w - f3);
    *(ushort4*)hp = H;
    *(ushort4*)lp = L2;
}

// ======================= prep kernels ====================================
__global__ void nafs_norms(const float* __restrict__ imgQ,
                           const float* __restrict__ imgV,
                           const float* __restrict__ txtK,
                           const float* __restrict__ txtV,
                           float* __restrict__ ws) {
    int row  = blockIdx.x * 4 + (threadIdx.x >> 6);
    int lane = threadIdx.x & 63;
    const float* src;
    int inv;
    if (row < 6144)       { src = imgQ + (size_t)row * ND;           inv = 1; }
    else if (row < 12544) { src = txtK + (size_t)(row - 6144) * ND;  inv = 1; }
    else if (row < 18688) { src = imgV + (size_t)(row - 12544) * ND; inv = 0; }
    else                  { src = txtV + (size_t)(row - 18688) * ND; inv = 0; }
    float ss = 0.f;
#pragma unroll
    for (int j = 0; j < 3; ++j) {
        float4 v = *(const float4*)(src + j * 256 + lane * 4);
        ss += v.x * v.x + v.y * v.y + v.z * v.z + v.w * v.w;
    }
#pragma unroll
    for (int off = 32; off > 0; off >>= 1) ss += __shfl_down(ss, off, 64);
    if (lane == 0) {
        float n = sqrtf(ss);
        ws[row] = inv ? (1.0f / (n + EPS)) : n;
    }
}

__global__ void nafs_convert(const float* __restrict__ txtK,
                             const float* __restrict__ imgQ,
                             const float* __restrict__ ws,
                             ushortt* __restrict__ khi, ushortt* __restrict__ klo,
                             ushortt* __restrict__ qhi, ushortt* __restrict__ qlo) {
    int row = blockIdx.x;
    int c4  = threadIdx.x;
    if (c4 >= 192) return;
    if (row < 8192) {
        int t = row >> 7, w = row & 127;
        size_t o = (size_t)row * ND + c4 * 4;
        if (w < NW) {
            float s = ws[6144 + t * NW + w];
            float4 v = *(const float4*)&txtK[((size_t)t * NW + w) * ND + c4 * 4];
            v.x *= s; v.y *= s; v.z *= s; v.w *= s;
            split_store(v, &khi[o], &klo[o]);
        } else {
            ushort4 z; z.x = z.y = z.z = z.w = 0;
            *(ushort4*)&khi[o] = z; *(ushort4*)&klo[o] = z;
        }
    } else {
        int q = row - 8192;
        float s = ws[q];
        float4 v = *(const float4*)&imgQ[(size_t)q * ND + c4 * 4];
        v.x *= s; v.y *= s; v.z *= s; v.w *= s;
        size_t o = (size_t)q * ND + c4 * 4;
        split_store(v, &qhi[o], &qlo[o]);
    }
}

__global__ void nafs_ttv(const float* __restrict__ txtV, ushortt* __restrict__ tvt) {
    __shared__ float sT[128 * 33];
    int t = blockIdx.x / 24, dt = blockIdx.x % 24, d0 = dt * 32;
    int tid = threadIdx.x;
    for (int idx = tid; idx < 128 * 8; idx += 256) {
        int w = idx >> 3, c4 = idx & 7;
        float4 v;
        if (w < NW) v = *(const float4*)&txtV[((size_t)t * NW + w) * ND + d0 + c4 * 4];
        else { v.x = v.y = v.z = v.w = 0.f; }
        float* p = &sT[w * 33 + c4 * 4];
        p[0] = v.x; p[1] = v.y; p[2] = v.z; p[3] = v.w;
    }
    __syncthreads();
    for (int idx = tid; idx < 32 * 32; idx += 256) {
        int w4 = idx & 31, c = idx >> 5;
        ushort4 o;
        o.x = f2bf(sT[(w4 * 4 + 0) * 33 + c]);
        o.y = f2bf(sT[(w4 * 4 + 1) * 33 + c]);
        o.z = f2bf(sT[(w4 * 4 + 2) * 33 + c]);
        o.w = f2bf(sT[(w4 * 4 + 3) * 33 + c]);
        *(ushort4*)&tvt[((size_t)t * ND + d0 + c) * 128 + w4 * 4] = o;
    }
}

__global__ void nafs_tiv(const float* __restrict__ imgV, ushortt* __restrict__ ivt) {
    __shared__ float sT[64 * 33];
    int i = blockIdx.x / 24, dt = blockIdx.x % 24, d0 = dt * 32;
    int tid = threadIdx.x;
    for (int idx = tid; idx < 64 * 8; idx += 256) {
        int r = idx >> 3, c4 = idx & 7;
        float4 v;
        if (r < NR) v = *(const float4*)&imgV[((size_t)i * NR + r) * ND + d0 + c4 * 4];
        else { v.x = v.y = v.z = v.w = 0.f; }
        float* p = &sT[r * 33 + c4 * 4];
        p[0] = v.x; p[1] = v.y; p[2] = v.z; p[3] = v.w;
    }
    __syncthreads();
    for (int idx = tid; idx < 16 * 32; idx += 256) {
        int r4 = idx & 15, c = idx >> 4;
        ushort4 o;
        o.x = f2bf(sT[(r4 * 4 + 0) * 33 + c]);
        o.y = f2bf(sT[(r4 * 4 + 1) * 33 + c]);
        o.z = f2bf(sT[(r4 * 4 + 2) * 33 + c]);
        o.w = f2bf(sT[(r4 * 4 + 3) * 33 + c]);
        *(ushort4*)&ivt[((size_t)i * ND + d0 + c) * 64 + r4 * 4] = o;
    }
}

// ======================= fused kernel (fast path) ========================
__global__ __launch_bounds__(256, 4)
void nafs_fused2(const float* __restrict__ imgV,
                 const int*  __restrict__ tlen,
                 const float* __restrict__ ws,
                 const ushortt* __restrict__ khi, const ushortt* __restrict__ klo,
                 const ushortt* __restrict__ qhi, const ushortt* __restrict__ qlo,
                 const ushortt* __restrict__ tvt, const ushortt* __restrict__ ivt,
                 float* __restrict__ out) {
    __shared__ __align__(16) float   aT[112 * 49];      // leaky(sim) fp32; later aliased by shATT2
    __shared__ __align__(16) ushortt shATT[48 * 128];   // attn bf16, XOR-swizzled blocks
    __shared__ float sInvW[NW], sInv2[NR], sCos1[NR], sCos2[112], sSS2[112], sDD2[112];
    ushortt* const shATT2 = (ushortt*)aT;               // attn2 bf16 [112][64], alias

    const int tid  = threadIdx.x;
    const int wv   = tid >> 6;
    const int lane = tid & 63;
    const int quad = lane >> 4;
    const int l15  = lane & 15;
    const int key  = l15 & 7;
    const int b    = blockIdx.x;
    // swizzle: concurrency tiles of 32 t x 32 i (balanced t/i working set)
    const int g    = b >> 10;
    const int s_   = b & 1023;
    const int t    = ((g & 1) << 5) | (s_ & 31);
    const int i    = ((g >> 1) << 5) | (s_ >> 5);
    const int L    = tlen[t];
    const float Lf = (float)L;

    const float* __restrict__ nVi = ws + 12544;
    const float* __restrict__ nVt = ws + 18688;

    if (tid < 112) { sSS2[tid] = 0.f; sDD2[tid] = 0.f; }

    // ---------------- Phase 1: sim via 3-pass split bf16 MFMA ------------
    const int m0  = wv, m1 = wv + 4;
    const int m1c = (m1 == 7) ? 6 : m1;    // wave3: load tile-6 dup (L2-hot) instead of zero tile
    const ushortt* pK0h = khi + ((size_t)t * 128 + m0 * 16 + l15) * ND + quad * 8;
    const ushortt* pK0l = klo + ((size_t)t * 128 + m0 * 16 + l15) * ND + quad * 8;
    const ushortt* pK1h = khi + ((size_t)t * 128 + m1c * 16 + l15) * ND + quad * 8;
    const ushortt* pK1l = klo + ((size_t)t * 128 + m1c * 16 + l15) * ND + quad * 8;
    const ushortt* pQh  = qhi + ((size_t)i * NR + l15) * ND + quad * 8;
    const ushortt* pQl  = qlo + ((size_t)i * NR + l15) * ND + quad * 8;

    f32x4 acc[2][3];
#pragma unroll
    for (int a = 0; a < 2; ++a)
#pragma unroll
        for (int n = 0; n < 3; ++n) acc[a][n] = (f32x4){0.f, 0.f, 0.f, 0.f};

    short8 cA0h, cA0l, cA1h, cA1l, cB0h, cB0l, cB1h, cB1l, cB2h, cB2l;
    cA0h = *(const short8*)(pK0h); cA0l = *(const short8*)(pK0l);
    cA1h = *(const short8*)(pK1h); cA1l = *(const short8*)(pK1l);
    cB0h = *(const short8*)(pQh);            cB0l = *(const short8*)(pQl);
    cB1h = *(const short8*)(pQh + 16 * ND);  cB1l = *(const short8*)(pQl + 16 * ND);
    cB2h = *(const short8*)(pQh + 32 * ND);  cB2l = *(const short8*)(pQl + 32 * ND);

    for (int dc = 0; dc < ND; dc += 32) {
        short8 nA0h, nA0l, nA1h, nA1l, nB0h, nB0l, nB1h, nB1l, nB2h, nB2l;
        int dn = dc + 32;
        if (dn < ND) {
            nA0h = *(const short8*)(pK0h + dn); nA0l = *(const short8*)(pK0l + dn);
            nA1h = *(const short8*)(pK1h + dn); nA1l = *(const short8*)(pK1l + dn);
            nB0h = *(const short8*)(pQh + dn);           nB0l = *(const short8*)(pQl + dn);
            nB1h = *(const short8*)(pQh + 16 * ND + dn); nB1l = *(const short8*)(pQl + 16 * ND + dn);
            nB2h = *(const short8*)(pQh + 32 * ND + dn); nB2l = *(const short8*)(pQl + 32 * ND + dn);
        }
        acc[0][0] = __builtin_amdgcn_mfma_f32_16x16x32_bf16(cA0h, cB0h, acc[0][0], 0, 0, 0);
        acc[0][0] = __builtin_amdgcn_mfma_f32_16x16x32_bf16(cA0h, cB0l, acc[0][0], 0, 0, 0);
        acc[0][0] = __builtin_amdgcn_mfma_f32_16x16x32_bf16(cA0l, cB0h, acc[0][0], 0, 0, 0);
        acc[0][1] = __builtin_amdgcn_mfma_f32_16x16x32_bf16(cA0h, cB1h, acc[0][1], 0, 0, 0);
        acc[0][1] = __builtin_amdgcn_mfma_f32_16x16x32_bf16(cA0h, cB1l, acc[0][1], 0, 0, 0);
        acc[0][1] = __builtin_amdgcn_mfma_f32_16x16x32_bf16(cA0l, cB1h, acc[0][1], 0, 0, 0);
        acc[0][2] = __builtin_amdgcn_mfma_f32_16x16x32_bf16(cA0h, cB2h, acc[0][2], 0, 0, 0);
        acc[0][2] = __builtin_amdgcn_mfma_f32_16x16x32_bf16(cA0h, cB2l, acc[0][2], 0, 0, 0);
        acc[0][2] = __builtin_amdgcn_mfma_f32_16x16x32_bf16(cA0l, cB2h, acc[0][2], 0, 0, 0);
        acc[1][0] = __builtin_amdgcn_mfma_f32_16x16x32_bf16(cA1h, cB0h, acc[1][0], 0, 0, 0);
        acc[1][0] = __builtin_amdgcn_mfma_f32_16x16x32_bf16(cA1h, cB0l, acc[1][0], 0, 0, 0);
        acc[1][0] = __builtin_amdgcn_mfma_f32_16x16x32_bf16(cA1l, cB0h, acc[1][0], 0, 0, 0);
        acc[1][1] = __builtin_amdgcn_mfma_f32_16x16x32_bf16(cA1h, cB1h, acc[1][1], 0, 0, 0);
        acc[1][1] = __builtin_amdgcn_mfma_f32_16x16x32_bf16(cA1h, cB1l, acc[1][1], 0, 0, 0);
        acc[1][1] = __builtin_amdgcn_mfma_f32_16x16x32_bf16(cA1l, cB1h, acc[1][1], 0, 0, 0);
        acc[1][2] = __builtin_amdgcn_mfma_f32_16x16x32_bf16(cA1h, cB2h, acc[1][2], 0, 0, 0);
        acc[1][2] = __builtin_amdgcn_mfma_f32_16x16x32_bf16(cA1h, cB2l, acc[1][2], 0, 0, 0);
        acc[1][2] = __builtin_amdgcn_mfma_f32_16x16x32_bf16(cA1l, cB2h, acc[1][2], 0, 0, 0);
        if (dn < ND) {
            cA0h = nA0h; cA0l = nA0l; cA1h = nA1h; cA1l = nA1l;
            cB0h = nB0h; cB0l = nB0l; cB1h = nB1h; cB1l = nB1l; cB2h = nB2h; cB2l = nB2l;
        }
    }
#pragma unroll
    for (int a = 0; a < 2; ++a) {
        int m = (a == 0) ? m0 : m1;
        if (m < 7) {
#pragma unroll
            for (int n = 0; n < 3; ++n) {
#pragma unroll
                for (int reg = 0; reg < 4; ++reg) {
                    float s = acc[a][n][reg];
                    aT[(m * 16 + quad * 4 + reg) * 49 + n * 16 + l15] = (s > 0.f) ? s : 0.1f * s;
                }
            }
        }
    }
    __syncthreads();

    // ---------------- Phase 2: norms + both attentions -------------------
    if (tid < NW) {
        float ssum = 0.f;
#pragma unroll 8
        for (int r = 0; r < NR; ++r) { float v = aT[tid * 49 + r]; ssum += v * v; }
        sInvW[tid] = 1.0f / (sqrtf(ssum) + EPS);
    } else if (tid >= 128 && tid < 128 + NR) {
        int r = tid - 128;
        float ssum = 0.f;
        for (int w = 0; w < L; ++w) { float v = aT[w * 49 + r]; ssum += v * v; }
        sInv2[r] = 1.0f / (sqrtf(ssum) + EPS);
    }
    __syncthreads();

    // branch-1 attn: writes shATT (separate region) while aT still live
    for (int r = wv; r < NR; r += 4) {
        int w1 = lane, w2 = lane + 64;
        int v1ok = (w1 < L), v2ok = (w2 < L);
        float v1 = v1ok ? aT[w1 * 49 + r] * sInvW[w1] * LAMB : -1e30f;
        float v2 = v2ok ? aT[w2 * 49 + r] * sInvW[w2] * LAMB : -1e30f;
        float m  = wredmax(fmaxf(v1, v2));
        float e1 = v1ok ? expf(v1 - m) : 0.f;
        float e2 = v2ok ? expf(v2 - m) : 0.f;
        float inv = 1.0f / wredsum(e1 + e2);
        float p1 = e1 * inv, p2 = e2 * inv;
        float S1 = wredsum(p1 + p2);
        float t1 = ((p1 * Lf - S1) > 0.f) ? p1 : 0.f;
        float t2 = ((p2 * Lf - S1) > 0.f) ? p2 : 0.f;
        float S2 = wredsum(t1 + t2);
        float iS2 = 1.0f / ((S2 > 0.f) ? S2 : 1.0f);
        shATT[r * 128 + (((w1 >> 3) ^ (r & 7)) << 3) + (w1 & 7)] = f2bf(t1 * iS2);
        shATT[r * 128 + (((w2 >> 3) ^ (r & 7)) << 3) + (w2 & 7)] = f2bf(t2 * iS2);
    }
    // branch-2 attn2: reads aT, stages values in REGISTERS (shATT2 aliases aT)
    float s2v[28];
#pragma unroll
    for (int k = 0; k < 28; ++k) {
        int w = wv + 4 * k;
        float val = 0.f;
        if (w < L) {
            int rok = (lane < NR);
            float v = rok ? aT[w * 49 + lane] * sInv2[lane] * LAMB : -1e30f;
            float m = wredmax(v);
            float e = rok ? expf(v - m) : 0.f;
            float inv = 1.0f / wredsum(e);
            float p = e * inv;
            float S1 = wredsum(p);
            float tm = ((p * 48.0f - S1) > 0.f) ? p : 0.f;
            float S2 = wredsum(tm);
            float iS2 = 1.0f / ((S2 > 0.f) ? S2 : 1.0f);
            val = tm * iS2;
        }
        s2v[k] = val;
    }
    __syncthreads();             // all aT reads complete block-wide
#pragma unroll
    for (int k = 0; k < 28; ++k) {
        int w = wv + 4 * k;
        shATT2[w * 64 + (((lane >> 3) ^ (w & 7)) << 3) + (lane & 7)] = f2bf(s2v[k]);
    }
    __syncthreads();

    // ---------------- B1: weiText cosine (waves 0-2, pipelined) ----------
    const int kk   = (L + 31) >> 5;     // only sectors holding w<L (rest exact-zero in attn)
    const int ntot = (L + 15) >> 4;
    if (wv < 3) {
        float ss1[4] = {0.f, 0.f, 0.f, 0.f}, dd1[4] = {0.f, 0.f, 0.f, 0.f};
        const ushortt* attRow = &shATT[(wv * 16 + l15) * 128];
        const ushortt* tvcB   = &tvt[((size_t)t * ND + l15) * 128 + quad * 8];
        const float*   ivB0   = &imgV[((size_t)i * NR + wv * 16 + quad * 4) * ND + l15];
        short8 af[4];
#pragma unroll
        for (int ks = 0; ks < 4; ++ks)        // loop-invariant attn fragments (LDS)
            af[ks] = *(const short8*)&attRow[(((ks * 4 + quad) ^ key)) << 3];
        short8 tA[4]; float vA[4];
#pragma unroll
        for (int ks = 0; ks < 4; ++ks)
            if (ks < kk) tA[ks] = *(const short8*)&tvcB[(size_t)ks * 32];
#pragma unroll
        for (int reg = 0; reg < 4; ++reg) vA[reg] = ivB0[reg * ND];
        for (int s = 0; s < 48; ++s) {        // d-offset = s*16
            short8 tN[4]; float vN[4];
            if (s < 47) {
                size_t d0 = (size_t)(s + 1) * 16;
#pragma unroll
                for (int ks = 0; ks < 4; ++ks)
                    if (ks < kk) tN[ks] = *(const short8*)&tvcB[d0 * 128 + ks * 32];
#pragma unroll
                for (int reg = 0; reg < 4; ++reg)
                    vN[reg] = ivB0[reg * ND + d0];
            }
            f32x4 u = (f32x4){0.f, 0.f, 0.f, 0.f};
#pragma unroll
            for (int ks = 0; ks < 4; ++ks)
                if (ks < kk) u = __builtin_amdgcn_mfma_f32_16x16x32_bf16(af[ks], tA[ks], u, 0, 0, 0);
#pragma unroll
            for (int reg = 0; reg < 4; ++reg) {
                float uu = u[reg];
                ss1[reg] = fmaf(uu, uu, ss1[reg]);
                dd1[reg] = fmaf(uu, vA[reg], dd1[reg]);
            }
            if (s < 47) {
#pragma unroll
                for (int q2 = 0; q2 < 4; ++q2) {
                    if (q2 < kk) tA[q2] = tN[q2];
                    vA[q2] = vN[q2];
                }
            }
        }
#pragma unroll
        for (int reg = 0; reg < 4; ++reg) {
            float s = ss1[reg], d = dd1[reg];
#pragma unroll
            for (int m = 1; m < 16; m <<= 1) { s += __shfl_xor(s, m, 64); d += __shfl_xor(d, m, 64); }
            if (l15 == 0) {
                int r = wv * 16 + quad * 4 + reg;
                float nu  = sqrtf(s);
                float num = d / (nu + EPS);
                float den = fmaxf(nVi[i * NR + r] * (nu / (nu + EPS)), EPS);
                sCos1[r] = num / den;
            }
        }
    }

    // ---------------- B2: weiImage cosine (ct outer, nt inner) -----------
    {
        const int ctb = (wv < 3) ? wv * 10 : 30;
        const int ctn = (wv < 3) ? 10 : 18;
        const ushortt* ivtB = &ivt[(size_t)i * ND * 64 + (size_t)l15 * 64 + quad * 8];
        const ushortt* tvpB = &tvt[((size_t)t * ND + quad * 4) * 128 + l15];
        float ssA[7], ddA[7];
#pragma unroll
        for (int nt = 0; nt < 7; ++nt) { ssA[nt] = 0.f; ddA[nt] = 0.f; }
        short8 a0 = *(const short8*)&ivtB[(size_t)ctb * 1024];
        short8 a1 = *(const short8*)&ivtB[(size_t)ctb * 1024 + 32];
        for (int j = 0; j < ctn; ++j) {
            int ct = ctb + j;
            short8 c0 = a0, c1 = a1;
            if (j + 1 < ctn) {                         // prefetch next ivt frags
                a0 = *(const short8*)&ivtB[(size_t)(ct + 1) * 1024];
                a1 = *(const short8*)&ivtB[(size_t)(ct + 1) * 1024 + 32];
            }
            const ushortt* tvr = &tvpB[(size_t)(ct * 16) * 128];
            for (int nt = 0; nt < ntot; ++nt) {
                ushortt tv0 = tvr[nt * 16];
                ushortt tv1 = tvr[128 + nt * 16];
                ushortt tv2 = tvr[256 + nt * 16];
                ushortt tv3 = tvr[384 + nt * 16];
                const ushortt* a2row = &shATT2[(nt * 16 + l15) * 64];
                short8 b0 = *(const short8*)&a2row[((quad ^ key)) << 3];
                short8 b1 = *(const short8*)&a2row[(((4 + quad) ^ key)) << 3];
                f32x4 u = (f32x4){0.f, 0.f, 0.f, 0.f};
                u = __builtin_amdgcn_mfma_f32_16x16x32_bf16(c0, b0, u, 0, 0, 0);
                u = __builtin_amdgcn_mfma_f32_16x16x32_bf16(c1, b1, u, 0, 0, 0);
                float ss = ssA[nt], dd = ddA[nt];
                ss = fmaf(u[0], u[0], ss); dd = fmaf(u[0], bf2f(tv0), dd);
                ss = fmaf(u[1], u[1], ss); dd = fmaf(u[1], bf2f(tv1), dd);
                ss = fmaf(u[2], u[2], ss); dd = fmaf(u[2], bf2f(tv2), dd);
                ss = fmaf(u[3], u[3], ss); dd = fmaf(u[3], bf2f(tv3), dd);
                ssA[nt] = ss; ddA[nt] = dd;
            }
        }
#pragma unroll
        for (int nt = 0; nt < 7; ++nt) {
            if (nt < ntot) {
                float ss = ssA[nt], dd = ddA[nt];
                ss += __shfl_xor(ss, 16, 64); dd += __shfl_xor(dd, 16, 64);
                ss += __shfl_xor(ss, 32, 64); dd += __shfl_xor(dd, 32, 64);
                if (quad == 0) {
                    atomicAdd(&sSS2[nt * 16 + l15], ss);
                    atomicAdd(&sDD2[nt * 16 + l15], dd);
                }
            }
        }
    }
    __syncthreads();
    if (tid < 112 && tid < L) {
        float s = sSS2[tid], d = sDD2[tid];
        float nu  = sqrtf(s);
        float num = d / (nu + EPS);
        float den = fmaxf(nVt[t * NW + tid] * (nu / (nu + EPS)), EPS);
        sCos2[tid] = num / den;
    }
    __syncthreads();
    if (tid == 0) {
        float s = 0.f;
        for (int r = 0; r < NR; ++r) s += sCos1[r];
        out[i * NT + t] = s * (1.0f / 48.0f);
    } else if (tid == 64) {
        float s = 0.f;
        for (int w = 0; w < L; ++w) s += sCos2[w];
        out[NI * NT + i * NT + t] = s / Lf;
    }
}

// ======================= fallback (round-2 kernel) =======================
#define A_KH   0
#define A_KL   4480
#define A_QH   8960
#define A_QL   10880
#define A_ATT  0
#define A_ATT2 6528
#define SHA_SZ 14592
#define B1_TVT 3200
#define B2_IVT 6656
#define SHB_SZ 4900

__global__ __launch_bounds__(256, 3)
void nafs_fused_fb(const float* __restrict__ imgQ,
                   const float* __restrict__ imgV,
                   const float* __restrict__ txtK,
                   const float* __restrict__ txtV,
                   const int*  __restrict__ tlen,
                   const float* __restrict__ ws,
                   float* __restrict__ out) {
    __shared__ ushortt shA[SHA_SZ];
    __shared__ float shB[SHB_SZ];
    __shared__ float sKs[NW], sQs[NR], sInvW[NW], sInv2[NR], sCos1[NR], sCos2[112];

    const int tid  = threadIdx.x;
    const int wv   = tid >> 6;
    const int lane = tid & 63;
    const int quad = lane >> 4;
    const int l15  = lane & 15;
    const int b    = blockIdx.x;
    const int t    = b >> 7;
    const int i    = b & 127;
    const int L    = tlen[t];
    const float Lf = (float)L;

    const float* __restrict__ invQ = ws;
    const float* __restrict__ invK = ws + 6144;
    const float* __restrict__ nVi  = ws + 12544;
    const float* __restrict__ nVt  = ws + 18688;

    const float* Kbase  = txtK + (size_t)t * (NW * ND);
    const float* Qbase  = imgQ + (size_t)i * (NR * ND);
    const float* TVbase = txtV + (size_t)t * (NW * ND);
    const float* IVbase = imgV + (size_t)i * (NR * ND);

    if (tid < NW)                  sKs[tid]       = invK[t * NW + tid];
    else if (tid < NW + NR)        sQs[tid - NW]  = invQ[i * NR + (tid - NW)];

    const int mt0 = wv * 2, mt1 = wv * 2 + 1;
    f32x4 acc[2][3];
#pragma unroll
    for (int a = 0; a < 2; ++a)
#pragma unroll
        for (int n = 0; n < 3; ++n) acc[a][n] = (f32x4){0.f, 0.f, 0.f, 0.f};

    for (int dc = 0; dc < ND; dc += 32) {
        __syncthreads();
        for (int idx = tid; idx < 112 * 8; idx += 256) {
            int w = idx >> 3, seg = idx & 7;
            float4 v;
            if (w < NW) {
                v = *(const float4*)(Kbase + (size_t)w * ND + dc + seg * 4);
                float s = sKs[w];
                v.x *= s; v.y *= s; v.z *= s; v.w *= s;
            } else { v.x = v.y = v.z = v.w = 0.f; }
            split_store(v, &shA[A_KH + w * 40 + seg * 4], &shA[A_KL + w * 40 + seg * 4]);
        }
        for (int idx = tid; idx < NR * 8; idx += 256) {
            int r = idx >> 3, seg = idx & 7;
            float4 v = *(const float4*)(Qbase + (size_t)r * ND + dc + seg * 4);
            float s = sQs[r];
            v.x *= s; v.y *= s; v.z *= s; v.w *= s;
            split_store(v, &shA[A_QH + r * 40 + seg * 4], &shA[A_QL + r * 40 + seg * 4]);
        }
        __syncthreads();
        short8 bh[3], bl[3];
#pragma unroll
        for (int n = 0; n < 3; ++n) {
            bh[n] = *(const short8*)&shA[A_QH + (n * 16 + l15) * 40 + quad * 8];
            bl[n] = *(const short8*)&shA[A_QL + (n * 16 + l15) * 40 + quad * 8];
        }
#pragma unroll
        for (int a = 0; a < 2; ++a) {
            int m = (a == 0) ? mt0 : mt1;
            if (m < 7) {
                short8 ah = *(const short8*)&shA[A_KH + (m * 16 + l15) * 40 + quad * 8];
                short8 al = *(const short8*)&shA[A_KL + (m * 16 + l15) * 40 + quad * 8];
#pragma unroll
                for (int n = 0; n < 3; ++n) {
                    acc[a][n] = __builtin_amdgcn_mfma_f32_16x16x32_bf16(ah, bh[n], acc[a][n], 0, 0, 0);
                    acc[a][n] = __builtin_amdgcn_mfma_f32_16x16x32_bf16(ah, bl[n], acc[a][n], 0, 0, 0);
                    acc[a][n] = __builtin_amdgcn_mfma_f32_16x16x32_bf16(al, bh[n], acc[a][n], 0, 0, 0);
                }
            }
        }
    }
    __syncthreads();
#pragma unroll
    for (int a = 0; a < 2; ++a) {
        int m = (a == 0) ? mt0 : mt1;
        if (m < 7) {
#pragma unroll
            for (int n = 0; n < 3; ++n) {
#pragma unroll
                for (int reg = 0; reg < 4; ++reg) {
                    int w = m * 16 + quad * 4 + reg;
                    if (w < NW) {
                        float s = acc[a][n][reg];
                        shB[w * 49 + n * 16 + l15] = (s > 0.f) ? s : 0.1f * s;
                    }
                }
            }
        }
    }
    __syncthreads();

    if (tid < NW) {
        float ssum = 0.f;
#pragma unroll 8
        for (int r = 0; r < NR; ++r) { float v = shB[tid * 49 + r]; ssum += v * v; }
        sInvW[tid] = 1.0f / (sqrtf(ssum) + EPS);
    } else if (tid >= 128 && tid < 128 + NR) {
        int r = tid - 128;
        float ssum = 0.f;
        for (int w = 0; w < L; ++w) { float v = shB[w * 49 + r]; ssum += v * v; }
        sInv2[r] = 1.0f / (sqrtf(ssum) + EPS);
    }
    __syncthreads();

    for (int r = wv; r < NR; r += 4) {
        int w1 = lane, w2 = lane + 64;
        int v1ok = (w1 < L), v2ok = (w2 < L);
        float v1 = v1ok ? shB[w1 * 49 + r] * sInvW[w1] * LAMB : -1e30f;
        float v2 = v2ok ? shB[w2 * 49 + r] * sInvW[w2] * LAMB : -1e30f;
        float m  = wredmax(fmaxf(v1, v2));
        float e1 = v1ok ? expf(v1 - m) : 0.f;
        float e2 = v2ok ? expf(v2 - m) : 0.f;
        float inv = 1.0f / wredsum(e1 + e2);
        float p1 = e1 * inv, p2 = e2 * inv;
        float S1 = wredsum(p1 + p2);
        float t1 = ((p1 * Lf - S1) > 0.f) ? p1 : 0.f;
        float t2 = ((p2 * Lf - S1) > 0.f) ? p2 : 0.f;
        float S2 = wredsum(t1 + t2);
        float iS2 = 1.0f / ((S2 > 0.f) ? S2 : 1.0f);
        shA[A_ATT + r * 136 + w1] = f2bf(t1 * iS2);
        shA[A_ATT + r * 136 + w2] = f2bf(t2 * iS2);
    }
    for (int w = wv; w < L; w += 4) {
        int rok = (lane < NR);
        float v = rok ? shB[w * 49 + lane] * sInv2[lane] * LAMB : -1e30f;
        float m = wredmax(v);
        float e = rok ? expf(v - m) : 0.f;
        float inv = 1.0f / wredsum(e);
        float p = e * inv;
        float S1 = wredsum(p);
        float tm = ((p * 48.0f - S1) > 0.f) ? p : 0.f;
        float S2 = wredsum(tm);
        float iS2 = 1.0f / ((S2 > 0.f) ? S2 : 1.0f);
        shA[A_ATT2 + w * 72 + lane] = f2bf(tm * iS2);
    }
    for (int w = L + wv; w < 112; w += 4) shA[A_ATT2 + w * 72 + lane] = 0;
    __syncthreads();

    ushortt* shBu = (ushortt*)shB;
    const int kk = (L + 31) >> 5;
    float ss1[4] = {0.f, 0.f, 0.f, 0.f}, dd1[4] = {0.f, 0.f, 0.f, 0.f};
    const int mt = wv;
    const int cgrp = tid >> 5, ccol = tid & 31;

    for (int cc = 0; cc < ND; cc += 32) {
        __syncthreads();
        for (int w = cgrp; w < 128; w += 8) {
            float val = (w < NW) ? TVbase[(size_t)w * ND + cc + ccol] : 0.f;
            shBu[B1_TVT + ccol * 136 + w] = f2bf(val);
        }
        for (int idx = tid; idx < NR * 8; idx += 256) {
            int r = idx >> 3, seg = idx & 7;
            float4 v = *(const float4*)(IVbase + (size_t)r * ND + cc + seg * 4);
            float* p = &shB[r * 33 + seg * 4];
            p[0] = v.x; p[1] = v.y; p[2] = v.z; p[3] = v.w;
        }
        __syncthreads();
        if (mt < 3) {
            f32x4 u[2] = {(f32x4){0.f,0.f,0.f,0.f}, (f32x4){0.f,0.f,0.f,0.f}};
            for (int ks = 0; ks < kk; ++ks) {
                short8 a = *(const short8*)&shA[A_ATT + (mt * 16 + l15) * 136 + ks * 32 + quad * 8];
#pragma unroll
                for (int n = 0; n < 2; ++n) {
                    short8 bb = *(const short8*)&shBu[B1_TVT + (n * 16 + l15) * 136 + ks * 32 + quad * 8];
                    u[n] = __builtin_amdgcn_mfma_f32_16x16x32_bf16(a, bb, u[n], 0, 0, 0);
                }
            }
#pragma unroll
            for (int n = 0; n < 2; ++n) {
#pragma unroll
                for (int reg = 0; reg < 4; ++reg) {
                    int r = mt * 16 + quad * 4 + reg;
                    float uu = u[n][reg];
                    ss1[reg] = fmaf(uu, uu, ss1[reg]);
                    dd1[reg] = fmaf(uu, shB[r * 33 + n * 16 + l15], dd1[reg]);
                }
            }
        }
    }
    if (mt < 3) {
#pragma unroll
        for (int reg = 0; reg < 4; ++reg) {
            float s = ss1[reg], d = dd1[reg];
#pragma unroll
            for (int m = 1; m < 16; m <<= 1) { s += __shfl_xor(s, m, 64); d += __shfl_xor(d, m, 64); }
            if (l15 == 0) {
                int r = mt * 16 + quad * 4 + reg;
                float nu  = sqrtf(s);
                float num = d / (nu + EPS);
                float den = fmaxf(nVi[i * NR + r] * (nu / (nu + EPS)), EPS);
                sCos1[r] = num / den;
            }
        }
    }

    const int ntot = (L + 15) >> 4;
    float ss2[2] = {0.f, 0.f}, dd2[2] = {0.f, 0.f};

    for (int cc = 0; cc < ND; cc += 32) {
        __syncthreads();
        for (int idx = tid; idx < NW * 8; idx += 256) {
            int w = idx >> 3, seg = idx & 7;
            float4 v = *(const float4*)(TVbase + (size_t)w * ND + cc + seg * 4);
            float* p = &shB[w * 33 + seg * 4];
            p[0] = v.x; p[1] = v.y; p[2] = v.z; p[3] = v.w;
        }
        for (int r = cgrp; r < 64; r += 8) {
            float val = (r < NR) ? IVbase[(size_t)r * ND + cc + ccol] : 0.f;
            shBu[B2_IVT + ccol * 72 + r] = f2bf(val);
        }
        __syncthreads();
#pragma unroll
        for (int pp = 0; pp < 2; ++pp) {
            int nt = wv + 4 * pp;
            if (nt < ntot) {
                f32x4 u[2] = {(f32x4){0.f,0.f,0.f,0.f}, (f32x4){0.f,0.f,0.f,0.f}};
#pragma unroll
                for (int ks = 0; ks < 2; ++ks) {
                    short8 bb = *(const short8*)&shA[A_ATT2 + (nt * 16 + l15) * 72 + ks * 32 + quad * 8];
#pragma unroll
                    for (int mm = 0; mm < 2; ++mm) {
                        short8 aa = *(const short8*)&shBu[B2_IVT + (mm * 16 + l15) * 72 + ks * 32 + quad * 8];
                        u[mm] = __builtin_amdgcn_mfma_f32_16x16x32_bf16(aa, bb, u[mm], 0, 0, 0);
                    }
                }
                int w = nt * 16 + l15;
                float tvok = (w < L) ? 1.f : 0.f;
#pragma unroll
                for (int mm = 0; mm < 2; ++mm) {
#pragma unroll
                    for (int reg = 0; reg < 4; ++reg) {
                        int c = mm * 16 + quad * 4 + reg;
                        float uu = u[mm][reg];
                        float tv = (w < L) ? shB[w * 33 + c] : 0.f;
                        ss2[pp] = fmaf(uu, uu, ss2[pp]);
                        dd2[pp] = fmaf(uu, tv * tvok, dd2[pp]);
                    }
                }
            }
        }
    }
#pragma unroll
    for (int pp = 0; pp < 2; ++pp) {
        int nt = wv + 4 * pp;
        if (nt < ntot) {
            float s = ss2[pp], d = dd2[pp];
            s += __shfl_xor(s, 16, 64); d += __shfl_xor(d, 16, 64);
            s += __shfl_xor(s, 32, 64); d += __shfl_xor(d, 32, 64);
            if (quad == 0) {
                int w = nt * 16 + l15;
                if (w < L) {
                    float nu  = sqrtf(s);
                    float num = d / (nu + EPS);
                    float den = fmaxf(nVt[t * NW + w] * (nu / (nu + EPS)), EPS);
                    sCos2[w] = num / den;
                }
            }
        }
    }
    __syncthreads();
    if (tid == 0) {
        float s = 0.f;
        for (int r = 0; r < NR; ++r) s += sCos1[r];
        out[i * NT + t] = s * (1.0f / 48.0f);
    } else if (tid == 64) {
        float s = 0.f;
        for (int w = 0; w < L; ++w) s += sCos2[w];
        out[NI * NT + i * NT + t] = s / Lf;
    }
}

extern "C" void kernel_launch(void* const* d_in, const int* in_sizes, int n_in,
                              void* d_out, int out_size, void* d_ws, size_t ws_size,
                              hipStream_t stream) {
    (void)in_sizes; (void)n_in; (void)out_size;
    const float* imgQ = (const float*)d_in[0];
    const float* imgV = (const float*)d_in[1];
    const float* txtK = (const float*)d_in[2];
    const float* txtV = (const float*)d_in[3];
    const int*   tlen = (const int*)d_in[4];
    float* ws  = (float*)d_ws;
    float* out = (float*)d_out;

    hipLaunchKernelGGL(nafs_norms, dim3(6272), dim3(256), 0, stream,
                       imgQ, imgV, txtK, txtV, ws);

    if (ws_size >= WS_NEED) {
        char* base = (char*)d_ws;
        ushortt* khi = (ushortt*)(base + OFF_KHI);
        ushortt* klo = (ushortt*)(base + OFF_KLO);
        ushortt* qhi = (ushortt*)(base + OFF_QHI);
        ushortt* qlo = (ushortt*)(base + OFF_QLO);
        ushortt* tvt = (ushortt*)(base + OFF_TVT);
        ushortt* ivt = (ushortt*)(base + OFF_IVT);
        hipLaunchKernelGGL(nafs_convert, dim3(14336), dim3(256), 0, stream,
                           txtK, imgQ, ws, khi, klo, qhi, qlo);
        hipLaunchKernelGGL(nafs_ttv, dim3(1536), dim3(256), 0, stream, txtV, tvt);
        hipLaunchKernelGGL(nafs_tiv, dim3(3072), dim3(256), 0, stream, imgV, ivt);
        hipLaunchKernelGGL(nafs_fused2, dim3(NT * NI), dim3(256), 0, stream,
                           imgV, tlen, ws, khi, klo, qhi, qlo, tvt, ivt, out);
    } else {
        hipLaunchKernelGGL(nafs_fused_fb, dim3(NT * NI), dim3(256), 0, stream,
                           imgQ, imgV, txtK, txtV, tlen, ws, out);
    }
}

// Round 6
// 1622.788 us; speedup vs baseline: 1.1653x; 1.0049x over previous
//
#include <hip/hip_runtime.h>

#define EPS   1e-8f
#define LAMB  20.0f
#define NI    128
#define NR    48
#define NT    64
#define NW    100
#define ND    768

typedef unsigned int uint;
typedef unsigned short ushortt;
typedef __attribute__((ext_vector_type(8))) short short8;
typedef __attribute__((ext_vector_type(4))) float f32x4;

// ======================= ws layout (fast path) ===========================
// floats: [0,6144) invQ, [6144,12544) invK, [12544,18688) nVi, [18688,25088) nVt
#define OFF_KHI  102400ULL      // bf16 [64][112][768] normalized K hi (w>=100 zero)
#define OFF_KLO  11112448ULL
#define OFF_QHI  22122496ULL    // bf16 [128][48][768] normalized Q hi
#define OFF_QLO  31559680ULL
#define OFF_TVB  40996864ULL    // bf16 [64][112][768] TV rows (w>=100 zero)
#define OFF_IVB  52006912ULL    // bf16 [128][48][768] IV rows
#define OFF_MH   61444096ULL    // bf16 [64][112][128] M=TV.TV^T hi (k-pad 112..127 zero)
#define OFF_ML   63279104ULL
#define OFF_HH   65114112ULL    // bf16 [128][48][64] H=IV.IV^T hi (k-pad 48..63 zero)
#define OFF_HL   65900544ULL
#define WS_NEED  66686976ULL

__device__ inline unsigned short f2bf(float f) {
    uint u = __float_as_uint(f);
    u = (u + 0x7fffu + ((u >> 16) & 1u)) >> 16;
    return (unsigned short)u;
}
__device__ inline float bf2f(unsigned short h) {
    return __uint_as_float((uint)h << 16);
}
__device__ inline float wredsum(float v) {
#pragma unroll
    for (int m = 1; m < 64; m <<= 1) v += __shfl_xor(v, m, 64);
    return v;
}
__device__ inline float wredmax(float v) {
#pragma unroll
    for (int m = 1; m < 64; m <<= 1) v = fmaxf(v, __shfl_xor(v, m, 64));
    return v;
}
__device__ inline void split_store(float4 v, ushortt* hp, ushortt* lp) {
    unsigned short h0 = f2bf(v.x), h1 = f2bf(v.y), h2 = f2bf(v.z), h3 = f2bf(v.w);
    float f0 = bf2f(h0), f1 = bf2f(h1), f2 = bf2f(h2), f3 = bf2f(h3);
    ushort4 H; H.x = h0; H.y = h1; H.z = h2; H.w = h3;
    ushort4 L2; L2.x = f2bf(v.x - f0); L2.y = f2bf(v.y - f1); L2.z = f2bf(v.z - f2); L2.w = f2bf(v.w - f3);
    *(ushort4*)hp = H;
    *(ushort4*)lp = L2;
}
// swizzled LDS element addresses (16B-block XOR swizzle)
__device__ inline int swzATT(int r, int w) {   // shATT[48][128]
    return r * 128 + ((((w >> 3) ^ (r & 7)) << 3) | (w & 7));
}
__device__ inline int swzATT2(int w, int r) {  // shATT2[112][64]
    return w * 64 + ((((r >> 3) ^ (w & 7)) << 3) | (r & 7));
}

// ======================= prep kernels ====================================
__global__ void nafs_norms(const float* __restrict__ imgQ,
                           const float* __restrict__ imgV,
                           const float* __restrict__ txtK,
                           const float* __restrict__ txtV,
                           float* __restrict__ ws) {
    int row  = blockIdx.x * 4 + (threadIdx.x >> 6);
    int lane = threadIdx.x & 63;
    const float* src;
    int inv;
    if (row < 6144)       { src = imgQ + (size_t)row * ND;           inv = 1; }
    else if (row < 12544) { src = txtK + (size_t)(row - 6144) * ND;  inv = 1; }
    else if (row < 18688) { src = imgV + (size_t)(row - 12544) * ND; inv = 0; }
    else                  { src = txtV + (size_t)(row - 18688) * ND; inv = 0; }
    float ss = 0.f;
#pragma unroll
    for (int j = 0; j < 3; ++j) {
        float4 v = *(const float4*)(src + j * 256 + lane * 4);
        ss += v.x * v.x + v.y * v.y + v.z * v.z + v.w * v.w;
    }
#pragma unroll
    for (int off = 32; off > 0; off >>= 1) ss += __shfl_down(ss, off, 64);
    if (lane == 0) {
        float n = sqrtf(ss);
        ws[row] = inv ? (1.0f / (n + EPS)) : n;
    }
}

// rows: [0,7168) K-norm-split, [7168,13312) Q-norm-split, [13312,20480) TVB cast, [20480,26624) IVB cast
__global__ void nafs_convert(const float* __restrict__ txtK,
                             const float* __restrict__ imgQ,
                             const float* __restrict__ txtV,
                             const float* __restrict__ imgV,
                             const float* __restrict__ ws,
                             ushortt* __restrict__ khi, ushortt* __restrict__ klo,
                             ushortt* __restrict__ qhi, ushortt* __restrict__ qlo,
                             ushortt* __restrict__ tvb, ushortt* __restrict__ ivb) {
    int row = blockIdx.x;
    int c4  = threadIdx.x;      // 0..191
    if (row < 7168) {
        int t = row / 112, w = row % 112;
        size_t o = (size_t)row * ND + c4 * 4;
        if (w < NW) {
            float s = ws[6144 + t * NW + w];
            float4 v = *(const float4*)&txtK[((size_t)t * NW + w) * ND + c4 * 4];
            v.x *= s; v.y *= s; v.z *= s; v.w *= s;
            split_store(v, &khi[o], &klo[o]);
        } else {
            ushort4 z; z.x = z.y = z.z = z.w = 0;
            *(ushort4*)&khi[o] = z; *(ushort4*)&klo[o] = z;
        }
    } else if (row < 13312) {
        int q = row - 7168;
        float s = ws[q];
        float4 v = *(const float4*)&imgQ[(size_t)q * ND + c4 * 4];
        v.x *= s; v.y *= s; v.z *= s; v.w *= s;
        size_t o = (size_t)q * ND + c4 * 4;
        split_store(v, &qhi[o], &qlo[o]);
    } else if (row < 20480) {
        int rr = row - 13312;
        int t = rr / 112, w = rr % 112;
        size_t o = (size_t)rr * ND + c4 * 4;
        ushort4 u; u.x = u.y = u.z = u.w = 0;
        if (w < NW) {
            float4 v = *(const float4*)&txtV[((size_t)t * NW + w) * ND + c4 * 4];
            u.x = f2bf(v.x); u.y = f2bf(v.y); u.z = f2bf(v.z); u.w = f2bf(v.w);
        }
        *(ushort4*)&tvb[o] = u;
    } else {
        int rr = row - 20480;
        size_t o = (size_t)rr * ND + c4 * 4;
        float4 v = *(const float4*)&imgV[(size_t)rr * ND + c4 * 4];
        ushort4 u; u.x = f2bf(v.x); u.y = f2bf(v.y); u.z = f2bf(v.z); u.w = f2bf(v.w);
        *(ushort4*)&ivb[o] = u;
    }
}

// M[t] = TVB @ TVB^T (112x112, k=768) -> bf16 hi/lo [112][128] (k-pad zero)
__global__ void nafs_gram_m(const ushortt* __restrict__ tvb,
                            ushortt* __restrict__ mh, ushortt* __restrict__ ml) {
    const int t = blockIdx.x;
    const int tid = threadIdx.x, wv = tid >> 6, lane = tid & 63;
    const int quad = lane >> 4, l15 = lane & 15;
    const ushortt* base = tvb + (size_t)t * 112 * ND;
    ushortt* mhB = mh + (size_t)t * 112 * 128;
    ushortt* mlB = ml + (size_t)t * 112 * 128;
#pragma unroll
    for (int a = 0; a < 2; ++a) {
        int m = wv + 4 * a;
        if (m < 7) {
            f32x4 c[7];
#pragma unroll
            for (int n = 0; n < 7; ++n) c[n] = (f32x4){0.f, 0.f, 0.f, 0.f};
            for (int dc = 0; dc < ND; dc += 32) {
                short8 av = *(const short8*)&base[(size_t)(m * 16 + l15) * ND + dc + quad * 8];
#pragma unroll
                for (int n = 0; n < 7; ++n) {
                    short8 bv = *(const short8*)&base[(size_t)(n * 16 + l15) * ND + dc + quad * 8];
                    c[n] = __builtin_amdgcn_mfma_f32_16x16x32_bf16(av, bv, c[n], 0, 0, 0);
                }
            }
#pragma unroll
            for (int n = 0; n < 7; ++n)
#pragma unroll
                for (int reg = 0; reg < 4; ++reg) {
                    int wr = m * 16 + quad * 4 + reg;
                    int wc = n * 16 + l15;
                    float v = c[n][reg];
                    ushortt h = f2bf(v);
                    mhB[wr * 128 + wc] = h;
                    mlB[wr * 128 + wc] = f2bf(v - bf2f(h));
                }
        }
    }
    for (int idx = tid; idx < 112 * 16; idx += 256) {
        int a = idx >> 4, b2 = 112 + (idx & 15);
        mhB[a * 128 + b2] = 0; mlB[a * 128 + b2] = 0;
    }
}

// H[i] = IVB @ IVB^T (48x48, k=768) -> bf16 hi/lo [48][64] (k-pad zero)
__global__ void nafs_gram_h(const ushortt* __restrict__ ivb,
                            ushortt* __restrict__ hh, ushortt* __restrict__ hl) {
    const int i = blockIdx.x;
    const int tid = threadIdx.x, wv = tid >> 6, lane = tid & 63;
    const int quad = lane >> 4, l15 = lane & 15;
    const ushortt* base = ivb + (size_t)i * NR * ND;
    ushortt* hhB = hh + (size_t)i * 48 * 64;
    ushortt* hlB = hl + (size_t)i * 48 * 64;
    if (wv < 3) {
        int m = wv;
        f32x4 c[3];
#pragma unroll
        for (int n = 0; n < 3; ++n) c[n] = (f32x4){0.f, 0.f, 0.f, 0.f};
        for (int dc = 0; dc < ND; dc += 32) {
            short8 av = *(const short8*)&base[(size_t)(m * 16 + l15) * ND + dc + quad * 8];
#pragma unroll
            for (int n = 0; n < 3; ++n) {
                short8 bv = *(const short8*)&base[(size_t)(n * 16 + l15) * ND + dc + quad * 8];
                c[n] = __builtin_amdgcn_mfma_f32_16x16x32_bf16(av, bv, c[n], 0, 0, 0);
            }
        }
#pragma unroll
        for (int n = 0; n < 3; ++n)
#pragma unroll
            for (int reg = 0; reg < 4; ++reg) {
                int rr = m * 16 + quad * 4 + reg;
                int rc = n * 16 + l15;
                float v = c[n][reg];
                ushortt h = f2bf(v);
                hhB[rr * 64 + rc] = h;
                hlB[rr * 64 + rc] = f2bf(v - bf2f(h));
            }
    }
    for (int idx = tid; idx < 48 * 16; idx += 256) {
        int a = idx >> 4, b2 = 48 + (idx & 15);
        hhB[a * 64 + b2] = 0; hlB[a * 64 + b2] = 0;
    }
}

// ======================= fused kernel (fast path) ========================
__global__ __launch_bounds__(256, 3)
void nafs_fused3(const int*  __restrict__ tlen,
                 const float* __restrict__ ws,
                 const ushortt* __restrict__ khi, const ushortt* __restrict__ klo,
                 const ushortt* __restrict__ qhi, const ushortt* __restrict__ qlo,
                 const ushortt* __restrict__ tvb, const ushortt* __restrict__ ivb,
                 const ushortt* __restrict__ mh, const ushortt* __restrict__ ml,
                 const ushortt* __restrict__ hh, const ushortt* __restrict__ hl,
                 float* __restrict__ out) {
    __shared__ __align__(16) float   aT[112 * 49];      // leaky(sim); later aliased by shATT2
    __shared__ __align__(16) ushortt shATT[48 * 128];   // attn bf16, XOR-swizzled
    __shared__ float sInvW[NW], sInv2[NR], sCos1[NR], sCos2[112];
    __shared__ float sSS1[NR], sDD1[NR], sSS2[112], sDD2[112];
    ushortt* const shATT2 = (ushortt*)aT;               // attn2 bf16 [112][64]

    const int tid  = threadIdx.x;
    const int wv   = tid >> 6;
    const int lane = tid & 63;
    const int quad = lane >> 4;
    const int l15  = lane & 15;
    const int key  = l15 & 7;
    const int b    = blockIdx.x;
    const int g    = b >> 10;
    const int s_   = b & 1023;
    const int t    = ((g & 1) << 5) | (s_ & 31);
    const int i    = ((g >> 1) << 5) | (s_ >> 5);
    const int L    = tlen[t];
    const float Lf = (float)L;

    const float* __restrict__ nVi = ws + 12544;
    const float* __restrict__ nVt = ws + 18688;

    if (tid < NR) { sSS1[tid] = 0.f; sDD1[tid] = 0.f; }

    // ---------------- Phase 1: sim via 3-pass split bf16 MFMA ------------
    const int m0  = wv, m1 = wv + 4;
    const int m1c = (m1 == 7) ? 6 : m1;    // wave3 loads dup tile-6 (discarded)
    const ushortt* pK0h = khi + ((size_t)t * 112 + m0 * 16 + l15) * ND + quad * 8;
    const ushortt* pK0l = klo + ((size_t)t * 112 + m0 * 16 + l15) * ND + quad * 8;
    const ushortt* pK1h = khi + ((size_t)t * 112 + m1c * 16 + l15) * ND + quad * 8;
    const ushortt* pK1l = klo + ((size_t)t * 112 + m1c * 16 + l15) * ND + quad * 8;
    const ushortt* pQh  = qhi + ((size_t)i * NR + l15) * ND + quad * 8;
    const ushortt* pQl  = qlo + ((size_t)i * NR + l15) * ND + quad * 8;

    f32x4 acc[2][3];
#pragma unroll
    for (int a = 0; a < 2; ++a)
#pragma unroll
        for (int n = 0; n < 3; ++n) acc[a][n] = (f32x4){0.f, 0.f, 0.f, 0.f};

    {
        short8 cA0h, cA0l, cA1h, cA1l, cB0h, cB0l, cB1h, cB1l, cB2h, cB2l;
        cA0h = *(const short8*)(pK0h); cA0l = *(const short8*)(pK0l);
        cA1h = *(const short8*)(pK1h); cA1l = *(const short8*)(pK1l);
        cB0h = *(const short8*)(pQh);            cB0l = *(const short8*)(pQl);
        cB1h = *(const short8*)(pQh + 16 * ND);  cB1l = *(const short8*)(pQl + 16 * ND);
        cB2h = *(const short8*)(pQh + 32 * ND);  cB2l = *(const short8*)(pQl + 32 * ND);
        for (int dc = 0; dc < ND; dc += 32) {
            short8 nA0h, nA0l, nA1h, nA1l, nB0h, nB0l, nB1h, nB1l, nB2h, nB2l;
            int dn = dc + 32;
            if (dn < ND) {
                nA0h = *(const short8*)(pK0h + dn); nA0l = *(const short8*)(pK0l + dn);
                nA1h = *(const short8*)(pK1h + dn); nA1l = *(const short8*)(pK1l + dn);
                nB0h = *(const short8*)(pQh + dn);           nB0l = *(const short8*)(pQl + dn);
                nB1h = *(const short8*)(pQh + 16 * ND + dn); nB1l = *(const short8*)(pQl + 16 * ND + dn);
                nB2h = *(const short8*)(pQh + 32 * ND + dn); nB2l = *(const short8*)(pQl + 32 * ND + dn);
            }
            acc[0][0] = __builtin_amdgcn_mfma_f32_16x16x32_bf16(cA0h, cB0h, acc[0][0], 0, 0, 0);
            acc[0][0] = __builtin_amdgcn_mfma_f32_16x16x32_bf16(cA0h, cB0l, acc[0][0], 0, 0, 0);
            acc[0][0] = __builtin_amdgcn_mfma_f32_16x16x32_bf16(cA0l, cB0h, acc[0][0], 0, 0, 0);
            acc[0][1] = __builtin_amdgcn_mfma_f32_16x16x32_bf16(cA0h, cB1h, acc[0][1], 0, 0, 0);
            acc[0][1] = __builtin_amdgcn_mfma_f32_16x16x32_bf16(cA0h, cB1l, acc[0][1], 0, 0, 0);
            acc[0][1] = __builtin_amdgcn_mfma_f32_16x16x32_bf16(cA0l, cB1h, acc[0][1], 0, 0, 0);
            acc[0][2] = __builtin_amdgcn_mfma_f32_16x16x32_bf16(cA0h, cB2h, acc[0][2], 0, 0, 0);
            acc[0][2] = __builtin_amdgcn_mfma_f32_16x16x32_bf16(cA0h, cB2l, acc[0][2], 0, 0, 0);
            acc[0][2] = __builtin_amdgcn_mfma_f32_16x16x32_bf16(cA0l, cB2h, acc[0][2], 0, 0, 0);
            acc[1][0] = __builtin_amdgcn_mfma_f32_16x16x32_bf16(cA1h, cB0h, acc[1][0], 0, 0, 0);
            acc[1][0] = __builtin_amdgcn_mfma_f32_16x16x32_bf16(cA1h, cB0l, acc[1][0], 0, 0, 0);
            acc[1][0] = __builtin_amdgcn_mfma_f32_16x16x32_bf16(cA1l, cB0h, acc[1][0], 0, 0, 0);
            acc[1][1] = __builtin_amdgcn_mfma_f32_16x16x32_bf16(cA1h, cB1h, acc[1][1], 0, 0, 0);
            acc[1][1] = __builtin_amdgcn_mfma_f32_16x16x32_bf16(cA1h, cB1l, acc[1][1], 0, 0, 0);
            acc[1][1] = __builtin_amdgcn_mfma_f32_16x16x32_bf16(cA1l, cB1h, acc[1][1], 0, 0, 0);
            acc[1][2] = __builtin_amdgcn_mfma_f32_16x16x32_bf16(cA1h, cB2h, acc[1][2], 0, 0, 0);
            acc[1][2] = __builtin_amdgcn_mfma_f32_16x16x32_bf16(cA1h, cB2l, acc[1][2], 0, 0, 0);
            acc[1][2] = __builtin_amdgcn_mfma_f32_16x16x32_bf16(cA1l, cB2h, acc[1][2], 0, 0, 0);
            if (dn < ND) {
                cA0h = nA0h; cA0l = nA0l; cA1h = nA1h; cA1l = nA1l;
                cB0h = nB0h; cB0l = nB0l; cB1h = nB1h; cB1l = nB1l; cB2h = nB2h; cB2l = nB2l;
            }
        }
    }
#pragma unroll
    for (int a = 0; a < 2; ++a) {
        int m = (a == 0) ? m0 : m1;
        if (m < 7) {
#pragma unroll
            for (int n = 0; n < 3; ++n)
#pragma unroll
                for (int reg = 0; reg < 4; ++reg) {
                    float s = acc[a][n][reg];
                    aT[(m * 16 + quad * 4 + reg) * 49 + n * 16 + l15] = (s > 0.f) ? s : 0.1f * s;
                }
        }
    }
    __syncthreads();

    // ---------------- Phase 2: norms + both attentions -------------------
    if (tid < NW) {
        float ssum = 0.f;
#pragma unroll 8
        for (int r = 0; r < NR; ++r) { float v = aT[tid * 49 + r]; ssum += v * v; }
        sInvW[tid] = 1.0f / (sqrtf(ssum) + EPS);
    } else if (tid >= 128 && tid < 128 + NR) {
        int r = tid - 128;
        float ssum = 0.f;
        for (int w = 0; w < L; ++w) { float v = aT[w * 49 + r]; ssum += v * v; }
        sInv2[r] = 1.0f / (sqrtf(ssum) + EPS);
    }
    __syncthreads();

    for (int r = wv; r < NR; r += 4) {
        int w1 = lane, w2 = lane + 64;
        int v1ok = (w1 < L), v2ok = (w2 < L);
        float v1 = v1ok ? aT[w1 * 49 + r] * sInvW[w1] * LAMB : -1e30f;
        float v2 = v2ok ? aT[w2 * 49 + r] * sInvW[w2] * LAMB : -1e30f;
        float m  = wredmax(fmaxf(v1, v2));
        float e1 = v1ok ? expf(v1 - m) : 0.f;
        float e2 = v2ok ? expf(v2 - m) : 0.f;
        float inv = 1.0f / wredsum(e1 + e2);
        float p1 = e1 * inv, p2 = e2 * inv;
        float S1 = wredsum(p1 + p2);
        float t1 = ((p1 * Lf - S1) > 0.f) ? p1 : 0.f;
        float t2 = ((p2 * Lf - S1) > 0.f) ? p2 : 0.f;
        float S2 = wredsum(t1 + t2);
        float iS2 = 1.0f / ((S2 > 0.f) ? S2 : 1.0f);
        shATT[swzATT(r, w1)] = f2bf(t1 * iS2);
        shATT[swzATT(r, w2)] = f2bf(t2 * iS2);
    }
    float s2v[28];
#pragma unroll
    for (int k = 0; k < 28; ++k) {
        int w = wv + 4 * k;
        float val = 0.f;
        if (w < L) {
            int rok = (lane < NR);
            float v = rok ? aT[w * 49 + lane] * sInv2[lane] * LAMB : -1e30f;
            float m = wredmax(v);
            float e = rok ? expf(v - m) : 0.f;
            float inv = 1.0f / wredsum(e);
            float p = e * inv;
            float S1 = wredsum(p);
            float tm = ((p * 48.0f - S1) > 0.f) ? p : 0.f;
            float S2 = wredsum(tm);
            float iS2 = 1.0f / ((S2 > 0.f) ? S2 : 1.0f);
            val = tm * iS2;
        }
        s2v[k] = val;
    }
    __syncthreads();
#pragma unroll
    for (int k = 0; k < 28; ++k) {
        int w = wv + 4 * k;
        shATT2[swzATT2(w, lane)] = f2bf(s2v[k]);
    }
    __syncthreads();

    // ---------------- G-GEMM: G = TVB @ IVB^T (112x48, k=768) ------------
    f32x4 gf[2][3];
#pragma unroll
    for (int a = 0; a < 2; ++a)
#pragma unroll
        for (int n = 0; n < 3; ++n) gf[a][n] = (f32x4){0.f, 0.f, 0.f, 0.f};
    {
        const int gm1c = m1c;   // same clamp as phase 1
        const ushortt* pA0 = tvb + ((size_t)t * 112 + m0 * 16 + l15) * ND + quad * 8;
        const ushortt* pA1 = tvb + ((size_t)t * 112 + gm1c * 16 + l15) * ND + quad * 8;
        const ushortt* pB  = ivb + ((size_t)i * NR + l15) * ND + quad * 8;
        short8 cA0 = *(const short8*)(pA0);
        short8 cA1 = *(const short8*)(pA1);
        short8 cB0 = *(const short8*)(pB);
        short8 cB1 = *(const short8*)(pB + 16 * ND);
        short8 cB2 = *(const short8*)(pB + 32 * ND);
        for (int dc = 0; dc < ND; dc += 32) {
            short8 nA0, nA1, nB0, nB1, nB2;
            int dn = dc + 32;
            if (dn < ND) {
                nA0 = *(const short8*)(pA0 + dn);
                nA1 = *(const short8*)(pA1 + dn);
                nB0 = *(const short8*)(pB + dn);
                nB1 = *(const short8*)(pB + 16 * ND + dn);
                nB2 = *(const short8*)(pB + 32 * ND + dn);
            }
            gf[0][0] = __builtin_amdgcn_mfma_f32_16x16x32_bf16(cA0, cB0, gf[0][0], 0, 0, 0);
            gf[0][1] = __builtin_amdgcn_mfma_f32_16x16x32_bf16(cA0, cB1, gf[0][1], 0, 0, 0);
            gf[0][2] = __builtin_amdgcn_mfma_f32_16x16x32_bf16(cA0, cB2, gf[0][2], 0, 0, 0);
            gf[1][0] = __builtin_amdgcn_mfma_f32_16x16x32_bf16(cA1, cB0, gf[1][0], 0, 0, 0);
            gf[1][1] = __builtin_amdgcn_mfma_f32_16x16x32_bf16(cA1, cB1, gf[1][1], 0, 0, 0);
            gf[1][2] = __builtin_amdgcn_mfma_f32_16x16x32_bf16(cA1, cB2, gf[1][2], 0, 0, 0);
            if (dn < ND) { cA0 = nA0; cA1 = nA1; cB0 = nB0; cB1 = nB1; cB2 = nB2; }
        }
    }
    // ---- G epilogue: dd2 (direct), dd1 (atomic) ----
    {
        float pd1[3] = {0.f, 0.f, 0.f};
#pragma unroll
        for (int a = 0; a < 2; ++a) {
            int m = wv + 4 * a;
            if (m < 7) {
#pragma unroll
                for (int reg = 0; reg < 4; ++reg) {
                    int w = m * 16 + quad * 4 + reg;
                    float p2 = 0.f;
#pragma unroll
                    for (int n = 0; n < 3; ++n) {
                        int r = n * 16 + l15;
                        float gv = gf[a][n][reg];
                        p2 = fmaf(gv, bf2f(shATT2[swzATT2(w, r)]), p2);
                        pd1[n] = fmaf(gv, bf2f(shATT[swzATT(r, w)]), pd1[n]);
                    }
                    p2 += __shfl_xor(p2, 1, 64); p2 += __shfl_xor(p2, 2, 64);
                    p2 += __shfl_xor(p2, 4, 64); p2 += __shfl_xor(p2, 8, 64);
                    if (l15 == 0) sDD2[w] = p2;
                }
            }
        }
#pragma unroll
        for (int n = 0; n < 3; ++n) {
            float p = pd1[n];
            p += __shfl_xor(p, 16, 64); p += __shfl_xor(p, 32, 64);
            if (quad == 0) atomicAdd(&sDD1[n * 16 + l15], p);
        }
    }

    // ---------------- Y-GEMM: Y = attn @ M^T, ss1 ------------------------
    {
        short8 af[3][4];
#pragma unroll
        for (int mt = 0; mt < 3; ++mt)
#pragma unroll
            for (int ks = 0; ks < 4; ++ks)
                af[mt][ks] = *(const short8*)&shATT[(mt * 16 + l15) * 128 + (((ks * 4 + quad) ^ key) << 3)];
        float ps[3][4];
#pragma unroll
        for (int mt = 0; mt < 3; ++mt)
#pragma unroll
            for (int reg = 0; reg < 4; ++reg) ps[mt][reg] = 0.f;
#pragma unroll
        for (int p = 0; p < 2; ++p) {
            int nt = wv + 4 * p;
            if (nt < 7) {
                const ushortt* pMh = mh + ((size_t)t * 112 + nt * 16 + l15) * 128 + quad * 8;
                const ushortt* pMl = ml + ((size_t)t * 112 + nt * 16 + l15) * 128 + quad * 8;
                short8 bh[4], bl[4];
#pragma unroll
                for (int ks = 0; ks < 4; ++ks) {
                    bh[ks] = *(const short8*)&pMh[ks * 32];
                    bl[ks] = *(const short8*)&pMl[ks * 32];
                }
                f32x4 y[3];
#pragma unroll
                for (int mt = 0; mt < 3; ++mt) y[mt] = (f32x4){0.f, 0.f, 0.f, 0.f};
#pragma unroll
                for (int mt = 0; mt < 3; ++mt)
#pragma unroll
                    for (int ks = 0; ks < 4; ++ks) {
                        y[mt] = __builtin_amdgcn_mfma_f32_16x16x32_bf16(af[mt][ks], bh[ks], y[mt], 0, 0, 0);
                        y[mt] = __builtin_amdgcn_mfma_f32_16x16x32_bf16(af[mt][ks], bl[ks], y[mt], 0, 0, 0);
                    }
                int wc = nt * 16 + l15;
#pragma unroll
                for (int mt = 0; mt < 3; ++mt)
#pragma unroll
                    for (int reg = 0; reg < 4; ++reg) {
                        int r = mt * 16 + quad * 4 + reg;
                        ps[mt][reg] = fmaf(y[mt][reg], bf2f(shATT[swzATT(r, wc)]), ps[mt][reg]);
                    }
            }
        }
#pragma unroll
        for (int mt = 0; mt < 3; ++mt)
#pragma unroll
            for (int reg = 0; reg < 4; ++reg) {
                float p = ps[mt][reg];
                p += __shfl_xor(p, 1, 64); p += __shfl_xor(p, 2, 64);
                p += __shfl_xor(p, 4, 64); p += __shfl_xor(p, 8, 64);
                if (l15 == 0) atomicAdd(&sSS1[mt * 16 + quad * 4 + reg], p);
            }
    }

    // ---------------- Z-GEMM: Z = attn2 @ H^T, ss2 -----------------------
    {
        short8 zbh[3][2], zbl[3][2];
#pragma unroll
        for (int n = 0; n < 3; ++n) {
            const ushortt* pHh = hh + ((size_t)i * NR + n * 16 + l15) * 64 + quad * 8;
            const ushortt* pHl = hl + ((size_t)i * NR + n * 16 + l15) * 64 + quad * 8;
#pragma unroll
            for (int ks = 0; ks < 2; ++ks) {
                zbh[n][ks] = *(const short8*)&pHh[ks * 32];
                zbl[n][ks] = *(const short8*)&pHl[ks * 32];
            }
        }
#pragma unroll
        for (int a = 0; a < 2; ++a) {
            int m = wv + 4 * a;
            if (m < 7) {
                f32x4 z[3];
#pragma unroll
                for (int n = 0; n < 3; ++n) z[n] = (f32x4){0.f, 0.f, 0.f, 0.f};
#pragma unroll
                for (int ks = 0; ks < 2; ++ks) {
                    short8 a2f = *(const short8*)&shATT2[(m * 16 + l15) * 64 + (((ks * 4 + quad) ^ key) << 3)];
#pragma unroll
                    for (int n = 0; n < 3; ++n) {
                        z[n] = __builtin_amdgcn_mfma_f32_16x16x32_bf16(a2f, zbh[n][ks], z[n], 0, 0, 0);
                        z[n] = __builtin_amdgcn_mfma_f32_16x16x32_bf16(a2f, zbl[n][ks], z[n], 0, 0, 0);
                    }
                }
#pragma unroll
                for (int reg = 0; reg < 4; ++reg) {
                    int w = m * 16 + quad * 4 + reg;
                    float p = 0.f;
#pragma unroll
                    for (int n = 0; n < 3; ++n)
                        p = fmaf(z[n][reg], bf2f(shATT2[swzATT2(w, n * 16 + l15)]), p);
                    p += __shfl_xor(p, 1, 64); p += __shfl_xor(p, 2, 64);
                    p += __shfl_xor(p, 4, 64); p += __shfl_xor(p, 8, 64);
                    if (l15 == 0) sSS2[w] = p;
                }
            }
        }
    }
    __syncthreads();

    // ---------------- cosine epilogue + output ---------------------------
    if (tid < NR) {
        float s = fmaxf(sSS1[tid], 0.f), d = sDD1[tid];
        float nu  = sqrtf(s);
        float num = d / (nu + EPS);
        float den = fmaxf(nVi[i * NR + tid] * (nu / (nu + EPS)), EPS);
        sCos1[tid] = num / den;
    } else if (tid >= 64 && tid < 176) {
        int w = tid - 64;
        if (w < L) {
            float s = fmaxf(sSS2[w], 0.f), d = sDD2[w];
            float nu  = sqrtf(s);
            float num = d / (nu + EPS);
            float den = fmaxf(nVt[t * NW + w] * (nu / (nu + EPS)), EPS);
            sCos2[w] = num / den;
        }
    }
    __syncthreads();
    if (tid == 0) {
        float s = 0.f;
        for (int r = 0; r < NR; ++r) s += sCos1[r];
        out[i * NT + t] = s * (1.0f / 48.0f);
    } else if (tid == 64) {
        float s = 0.f;
        for (int w = 0; w < L; ++w) s += sCos2[w];
        out[NI * NT + i * NT + t] = s / Lf;
    }
}

// ======================= fallback (ws too small) =========================
#define A_KH   0
#define A_KL   4480
#define A_QH   8960
#define A_QL   10880
#define A_ATT  0
#define A_ATT2 6528
#define SHA_SZ 14592
#define B1_TVT 3200
#define B2_IVT 6656
#define SHB_SZ 4900

__global__ __launch_bounds__(256, 3)
void nafs_fused_fb(const float* __restrict__ imgQ,
                   const float* __restrict__ imgV,
                   const float* __restrict__ txtK,
                   const float* __restrict__ txtV,
                   const int*  __restrict__ tlen,
                   const float* __restrict__ ws,
                   float* __restrict__ out) {
    __shared__ ushortt shA[SHA_SZ];
    __shared__ float shB[SHB_SZ];
    __shared__ float sKs[NW], sQs[NR], sInvW[NW], sInv2[NR], sCos1[NR], sCos2[112];

    const int tid  = threadIdx.x;
    const int wv   = tid >> 6;
    const int lane = tid & 63;
    const int quad = lane >> 4;
    const int l15  = lane & 15;
    const int b    = blockIdx.x;
    const int t    = b >> 7;
    const int i    = b & 127;
    const int L    = tlen[t];
    const float Lf = (float)L;

    const float* __restrict__ invQ = ws;
    const float* __restrict__ invK = ws + 6144;
    const float* __restrict__ nVi  = ws + 12544;
    const float* __restrict__ nVt  = ws + 18688;

    const float* Kbase  = txtK + (size_t)t * (NW * ND);
    const float* Qbase  = imgQ + (size_t)i * (NR * ND);
    const float* TVbase = txtV + (size_t)t * (NW * ND);
    const float* IVbase = imgV + (size_t)i * (NR * ND);

    if (tid < NW)                  sKs[tid]       = invK[t * NW + tid];
    else if (tid < NW + NR)        sQs[tid - NW]  = invQ[i * NR + (tid - NW)];

    const int mt0 = wv * 2, mt1 = wv * 2 + 1;
    f32x4 acc[2][3];
#pragma unroll
    for (int a = 0; a < 2; ++a)
#pragma unroll
        for (int n = 0; n < 3; ++n) acc[a][n] = (f32x4){0.f, 0.f, 0.f, 0.f};

    for (int dc = 0; dc < ND; dc += 32) {
        __syncthreads();
        for (int idx = tid; idx < 112 * 8; idx += 256) {
            int w = idx >> 3, seg = idx & 7;
            float4 v;
            if (w < NW) {
                v = *(const float4*)(Kbase + (size_t)w * ND + dc + seg * 4);
                float s = sKs[w];
                v.x *= s; v.y *= s; v.z *= s; v.w *= s;
            } else { v.x = v.y = v.z = v.w = 0.f; }
            split_store(v, &shA[A_KH + w * 40 + seg * 4], &shA[A_KL + w * 40 + seg * 4]);
        }
        for (int idx = tid; idx < NR * 8; idx += 256) {
            int r = idx >> 3, seg = idx & 7;
            float4 v = *(const float4*)(Qbase + (size_t)r * ND + dc + seg * 4);
            float s = sQs[r];
            v.x *= s; v.y *= s; v.z *= s; v.w *= s;
            split_store(v, &shA[A_QH + r * 40 + seg * 4], &shA[A_QL + r * 40 + seg * 4]);
        }
        __syncthreads();
        short8 bh[3], bl[3];
#pragma unroll
        for (int n = 0; n < 3; ++n) {
            bh[n] = *(const short8*)&shA[A_QH + (n * 16 + l15) * 40 + quad * 8];
            bl[n] = *(const short8*)&shA[A_QL + (n * 16 + l15) * 40 + quad * 8];
        }
#pragma unroll
        for (int a = 0; a < 2; ++a) {
            int m = (a == 0) ? mt0 : mt1;
            if (m < 7) {
                short8 ah = *(const short8*)&shA[A_KH + (m * 16 + l15) * 40 + quad * 8];
                short8 al = *(const short8*)&shA[A_KL + (m * 16 + l15) * 40 + quad * 8];
#pragma unroll
                for (int n = 0; n < 3; ++n) {
                    acc[a][n] = __builtin_amdgcn_mfma_f32_16x16x32_bf16(ah, bh[n], acc[a][n], 0, 0, 0);
                    acc[a][n] = __builtin_amdgcn_mfma_f32_16x16x32_bf16(ah, bl[n], acc[a][n], 0, 0, 0);
                    acc[a][n] = __builtin_amdgcn_mfma_f32_16x16x32_bf16(al, bh[n], acc[a][n], 0, 0, 0);
                }
            }
        }
    }
    __syncthreads();
#pragma unroll
    for (int a = 0; a < 2; ++a) {
        int m = (a == 0) ? mt0 : mt1;
        if (m < 7) {
#pragma unroll
            for (int n = 0; n < 3; ++n)
#pragma unroll
                for (int reg = 0; reg < 4; ++reg) {
                    int w = m * 16 + quad * 4 + reg;
                    if (w < NW) {
                        float s = acc[a][n][reg];
                        shB[w * 49 + n * 16 + l15] = (s > 0.f) ? s : 0.1f * s;
                    }
                }
        }
    }
    __syncthreads();

    if (tid < NW) {
        float ssum = 0.f;
#pragma unroll 8
        for (int r = 0; r < NR; ++r) { float v = shB[tid * 49 + r]; ssum += v * v; }
        sInvW[tid] = 1.0f / (sqrtf(ssum) + EPS);
    } else if (tid >= 128 && tid < 128 + NR) {
        int r = tid - 128;
        float ssum = 0.f;
        for (int w = 0; w < L; ++w) { float v = shB[w * 49 + r]; ssum += v * v; }
        sInv2[r] = 1.0f / (sqrtf(ssum) + EPS);
    }
    __syncthreads();

    for (int r = wv; r < NR; r += 4) {
        int w1 = lane, w2 = lane + 64;
        int v1ok = (w1 < L), v2ok = (w2 < L);
        float v1 = v1ok ? shB[w1 * 49 + r] * sInvW[w1] * LAMB : -1e30f;
        float v2 = v2ok ? shB[w2 * 49 + r] * sInvW[w2] * LAMB : -1e30f;
        float m  = wredmax(fmaxf(v1, v2));
        float e1 = v1ok ? expf(v1 - m) : 0.f;
        float e2 = v2ok ? expf(v2 - m) : 0.f;
        float inv = 1.0f / wredsum(e1 + e2);
        float p1 = e1 * inv, p2 = e2 * inv;
        float S1 = wredsum(p1 + p2);
        float t1 = ((p1 * Lf - S1) > 0.f) ? p1 : 0.f;
        float t2 = ((p2 * Lf - S1) > 0.f) ? p2 : 0.f;
        float S2 = wredsum(t1 + t2);
        float iS2 = 1.0f / ((S2 > 0.f) ? S2 : 1.0f);
        shA[A_ATT + r * 136 + w1] = f2bf(t1 * iS2);
        shA[A_ATT + r * 136 + w2] = f2bf(t2 * iS2);
    }
    for (int w = wv; w < L; w += 4) {
        int rok = (lane < NR);
        float v = rok ? shB[w * 49 + lane] * sInv2[lane] * LAMB : -1e30f;
        float m = wredmax(v);
        float e = rok ? expf(v - m) : 0.f;
        float inv = 1.0f / wredsum(e);
        float p = e * inv;
        float S1 = wredsum(p);
        float tm = ((p * 48.0f - S1) > 0.f) ? p : 0.f;
        float S2 = wredsum(tm);
        float iS2 = 1.0f / ((S2 > 0.f) ? S2 : 1.0f);
        shA[A_ATT2 + w * 72 + lane] = f2bf(tm * iS2);
    }
    for (int w = L + wv; w < 112; w += 4) shA[A_ATT2 + w * 72 + lane] = 0;
    __syncthreads();

    ushortt* shBu = (ushortt*)shB;
    const int kk = (L + 31) >> 5;
    float ss1[4] = {0.f, 0.f, 0.f, 0.f}, dd1[4] = {0.f, 0.f, 0.f, 0.f};
    const int mt = wv;
    const int cgrp = tid >> 5, ccol = tid & 31;

    for (int cc = 0; cc < ND; cc += 32) {
        __syncthreads();
        for (int w = cgrp; w < 128; w += 8) {
            float val = (w < NW) ? TVbase[(size_t)w * ND + cc + ccol] : 0.f;
            shBu[B1_TVT + ccol * 136 + w] = f2bf(val);
        }
        for (int idx = tid; idx < NR * 8; idx += 256) {
            int r = idx >> 3, seg = idx & 7;
            float4 v = *(const float4*)(IVbase + (size_t)r * ND + cc + seg * 4);
            float* p = &shB[r * 33 + seg * 4];
            p[0] = v.x; p[1] = v.y; p[2] = v.z; p[3] = v.w;
        }
        __syncthreads();
        if (mt < 3) {
            f32x4 u[2] = {(f32x4){0.f,0.f,0.f,0.f}, (f32x4){0.f,0.f,0.f,0.f}};
            for (int ks = 0; ks < kk; ++ks) {
                short8 a = *(const short8*)&shA[A_ATT + (mt * 16 + l15) * 136 + ks * 32 + quad * 8];
#pragma unroll
                for (int n = 0; n < 2; ++n) {
                    short8 bb = *(const short8*)&shBu[B1_TVT + (n * 16 + l15) * 136 + ks * 32 + quad * 8];
                    u[n] = __builtin_amdgcn_mfma_f32_16x16x32_bf16(a, bb, u[n], 0, 0, 0);
                }
            }
#pragma unroll
            for (int n = 0; n < 2; ++n)
#pragma unroll
                for (int reg = 0; reg < 4; ++reg) {
                    int r = mt * 16 + quad * 4 + reg;
                    float uu = u[n][reg];
                    ss1[reg] = fmaf(uu, uu, ss1[reg]);
                    dd1[reg] = fmaf(uu, shB[r * 33 + n * 16 + l15], dd1[reg]);
                }
        }
    }
    if (mt < 3) {
#pragma unroll
        for (int reg = 0; reg < 4; ++reg) {
            float s = ss1[reg], d = dd1[reg];
#pragma unroll
            for (int m = 1; m < 16; m <<= 1) { s += __shfl_xor(s, m, 64); d += __shfl_xor(d, m, 64); }
            if (l15 == 0) {
                int r = mt * 16 + quad * 4 + reg;
                float nu  = sqrtf(s);
                float num = d / (nu + EPS);
                float den = fmaxf(nVi[i * NR + r] * (nu / (nu + EPS)), EPS);
                sCos1[r] = num / den;
            }
        }
    }

    const int ntot = (L + 15) >> 4;
    float ss2[2] = {0.f, 0.f}, dd2[2] = {0.f, 0.f};

    for (int cc = 0; cc < ND; cc += 32) {
        __syncthreads();
        for (int idx = tid; idx < NW * 8; idx += 256) {
            int w = idx >> 3, seg = idx & 7;
            float4 v = *(const float4*)(TVbase + (size_t)w * ND + cc + seg * 4);
            float* p = &shB[w * 33 + seg * 4];
            p[0] = v.x; p[1] = v.y; p[2] = v.z; p[3] = v.w;
        }
        for (int r = cgrp; r < 64; r += 8) {
            float val = (r < NR) ? IVbase[(size_t)r * ND + cc + ccol] : 0.f;
            shBu[B2_IVT + ccol * 72 + r] = f2bf(val);
        }
        __syncthreads();
#pragma unroll
        for (int pp = 0; pp < 2; ++pp) {
            int nt = wv + 4 * pp;
            if (nt < ntot) {
                f32x4 u[2] = {(f32x4){0.f,0.f,0.f,0.f}, (f32x4){0.f,0.f,0.f,0.f}};
#pragma unroll
                for (int ks = 0; ks < 2; ++ks) {
                    short8 bb = *(const short8*)&shA[A_ATT2 + (nt * 16 + l15) * 72 + ks * 32 + quad * 8];
#pragma unroll
                    for (int mm = 0; mm < 2; ++mm) {
                        short8 aa = *(const short8*)&shBu[B2_IVT + (mm * 16 + l15) * 72 + ks * 32 + quad * 8];
                        u[mm] = __builtin_amdgcn_mfma_f32_16x16x32_bf16(aa, bb, u[mm], 0, 0, 0);
                    }
                }
                int w = nt * 16 + l15;
                float tvok = (w < L) ? 1.f : 0.f;
#pragma unroll
                for (int mm = 0; mm < 2; ++mm)
#pragma unroll
                    for (int reg = 0; reg < 4; ++reg) {
                        int c = mm * 16 + quad * 4 + reg;
                        float uu = u[mm][reg];
                        float tv = (w < L) ? shB[w * 33 + c] : 0.f;
                        ss2[pp] = fmaf(uu, uu, ss2[pp]);
                        dd2[pp] = fmaf(uu, tv * tvok, dd2[pp]);
                    }
            }
        }
    }
#pragma unroll
    for (int pp = 0; pp < 2; ++pp) {
        int nt = wv + 4 * pp;
        if (nt < ntot) {
            float s = ss2[pp], d = dd2[pp];
            s += __shfl_xor(s, 16, 64); d += __shfl_xor(d, 16, 64);
            s += __shfl_xor(s, 32, 64); d += __shfl_xor(d, 32, 64);
            if (quad == 0) {
                int w = nt * 16 + l15;
                if (w < L) {
                    float nu  = sqrtf(s);
                    float num = d / (nu + EPS);
                    float den = fmaxf(nVt[t * NW + w] * (nu / (nu + EPS)), EPS);
                    sCos2[w] = num / den;
                }
            }
        }
    }
    __syncthreads();
    if (tid == 0) {
        float s = 0.f;
        for (int r = 0; r < NR; ++r) s += sCos1[r];
        out[i * NT + t] = s * (1.0f / 48.0f);
    } else if (tid == 64) {
        float s = 0.f;
        for (int w = 0; w < L; ++w) s += sCos2[w];
        out[NI * NT + i * NT + t] = s / Lf;
    }
}

extern "C" void kernel_launch(void* const* d_in, const int* in_sizes, int n_in,
                              void* d_out, int out_size, void* d_ws, size_t ws_size,
                              hipStream_t stream) {
    (void)in_sizes; (void)n_in; (void)out_size;
    const float* imgQ = (const float*)d_in[0];
    const float* imgV = (const float*)d_in[1];
    const float* txtK = (const float*)d_in[2];
    const float* txtV = (const float*)d_in[3];
    const int*   tlen = (const int*)d_in[4];
    float* ws  = (float*)d_ws;
    float* out = (float*)d_out;

    hipLaunchKernelGGL(nafs_norms, dim3(6272), dim3(256), 0, stream,
                       imgQ, imgV, txtK, txtV, ws);

    if (ws_size >= WS_NEED) {
        char* base = (char*)d_ws;
        ushortt* khi = (ushortt*)(base + OFF_KHI);
        ushortt* klo = (ushortt*)(base + OFF_KLO);
        ushortt* qhi = (ushortt*)(base + OFF_QHI);
        ushortt* qlo = (ushortt*)(base + OFF_QLO);
        ushortt* tvb = (ushortt*)(base + OFF_TVB);
        ushortt* ivb = (ushortt*)(base + OFF_IVB);
        ushortt* mh  = (ushortt*)(base + OFF_MH);
        ushortt* ml  = (ushortt*)(base + OFF_ML);
        ushortt* hh  = (ushortt*)(base + OFF_HH);
        ushortt* hl  = (ushortt*)(base + OFF_HL);
        hipLaunchKernelGGL(nafs_convert, dim3(26624), dim3(192), 0, stream,
                           txtK, imgQ, txtV, imgV, ws, khi, klo, qhi, qlo, tvb, ivb);
        hipLaunchKernelGGL(nafs_gram_m, dim3(64), dim3(256), 0, stream, tvb, mh, ml);
        hipLaunchKernelGGL(nafs_gram_h, dim3(128), dim3(256), 0, stream, ivb, hh, hl);
        hipLaunchKernelGGL(nafs_fused3, dim3(NT * NI), dim3(256), 0, stream,
                           tlen, ws, khi, klo, qhi, qlo, tvb, ivb, mh, ml, hh, hl, out);
    } else {
        hipLaunchKernelGGL(nafs_fused_fb, dim3(NT * NI), dim3(256), 0, stream,
                           imgQ, imgV, txtK, txtV, tlen, ws, out);
    }
}

// Round 7
// 1531.620 us; speedup vs baseline: 1.2346x; 1.0595x over previous
//
#include <hip/hip_runtime.h>

#define EPS   1e-8f
#define LAMB  20.0f
#define NI    128
#define NR    48
#define NT    64
#define NW    100
#define ND    768

typedef unsigned int uint;
typedef unsigned short ushortt;
typedef __attribute__((ext_vector_type(8))) short short8;
typedef __attribute__((ext_vector_type(4))) float f32x4;

// ======================= ws layout (fast path) ===========================
// floats: [0,6144) invQ, [6144,12544) invK, [12544,18688) nVi, [18688,25088) nVt
#define OFF_KHI  102400ULL      // bf16 [64][112][768] normalized K hi (w>=100 zero)
#define OFF_KLO  11112448ULL
#define OFF_QHI  22122496ULL    // bf16 [128][48][768] normalized Q hi
#define OFF_QLO  31559680ULL
#define OFF_TVB  40996864ULL    // bf16 [64][112][768] TV rows (w>=100 zero)
#define OFF_IVB  52006912ULL    // bf16 [128][48][768] IV rows
#define OFF_MH   61444096ULL    // bf16 [64][112][128] M=TV.TV^T hi (k-pad zero)
#define OFF_ML   63279104ULL
#define OFF_HH   65114112ULL    // bf16 [128][48][64] H=IV.IV^T hi (k-pad zero)
#define OFF_HL   65900544ULL
#define WS_NEED  66686976ULL

__device__ inline unsigned short f2bf(float f) {
    uint u = __float_as_uint(f);
    u = (u + 0x7fffu + ((u >> 16) & 1u)) >> 16;
    return (unsigned short)u;
}
__device__ inline float bf2f(unsigned short h) {
    return __uint_as_float((uint)h << 16);
}
__device__ inline void split_store(float4 v, ushortt* hp, ushortt* lp) {
    unsigned short h0 = f2bf(v.x), h1 = f2bf(v.y), h2 = f2bf(v.z), h3 = f2bf(v.w);
    float f0 = bf2f(h0), f1 = bf2f(h1), f2 = bf2f(h2), f3 = bf2f(h3);
    ushort4 H; H.x = h0; H.y = h1; H.z = h2; H.w = h3;
    ushort4 L2; L2.x = f2bf(v.x - f0); L2.y = f2bf(v.y - f1); L2.z = f2bf(v.z - f2); L2.w = f2bf(v.w - f3);
    *(ushort4*)hp = H;
    *(ushort4*)lp = L2;
}
// swizzled LDS element addresses (16B-block XOR swizzle)
__device__ inline int swzATT(int r, int w) {   // shATT[48][128]
    return r * 128 + ((((w >> 3) ^ (r & 7)) << 3) | (w & 7));
}
__device__ inline int swzATT2(int w, int r) {  // shATT2[112][64]
    return w * 64 + ((((r >> 3) ^ (w & 7)) << 3) | (r & 7));
}
__device__ inline float wredsum(float v) {
#pragma unroll
    for (int m = 1; m < 64; m <<= 1) v += __shfl_xor(v, m, 64);
    return v;
}
__device__ inline float wredmax(float v) {
#pragma unroll
    for (int m = 1; m < 64; m <<= 1) v = fmaxf(v, __shfl_xor(v, m, 64));
    return v;
}

// ======================= prep kernels ====================================
__global__ void nafs_norms(const float* __restrict__ imgQ,
                           const float* __restrict__ imgV,
                           const float* __restrict__ txtK,
                           const float* __restrict__ txtV,
                           float* __restrict__ ws) {
    int row  = blockIdx.x * 4 + (threadIdx.x >> 6);
    int lane = threadIdx.x & 63;
    const float* src;
    int inv;
    if (row < 6144)       { src = imgQ + (size_t)row * ND;           inv = 1; }
    else if (row < 12544) { src = txtK + (size_t)(row - 6144) * ND;  inv = 1; }
    else if (row < 18688) { src = imgV + (size_t)(row - 12544) * ND; inv = 0; }
    else                  { src = txtV + (size_t)(row - 18688) * ND; inv = 0; }
    float ss = 0.f;
#pragma unroll
    for (int j = 0; j < 3; ++j) {
        float4 v = *(const float4*)(src + j * 256 + lane * 4);
        ss += v.x * v.x + v.y * v.y + v.z * v.z + v.w * v.w;
    }
#pragma unroll
    for (int off = 32; off > 0; off >>= 1) ss += __shfl_down(ss, off, 64);
    if (lane == 0) {
        float n = sqrtf(ss);
        ws[row] = inv ? (1.0f / (n + EPS)) : n;
    }
}

// rows: [0,7168) K-norm-split, [7168,13312) Q-norm-split, [13312,20480) TVB cast, [20480,26624) IVB cast
__global__ void nafs_convert(const float* __restrict__ txtK,
                             const float* __restrict__ imgQ,
                             const float* __restrict__ txtV,
                             const float* __restrict__ imgV,
                             const float* __restrict__ ws,
                             ushortt* __restrict__ khi, ushortt* __restrict__ klo,
                             ushortt* __restrict__ qhi, ushortt* __restrict__ qlo,
                             ushortt* __restrict__ tvb, ushortt* __restrict__ ivb) {
    int row = blockIdx.x;
    int c4  = threadIdx.x;      // 0..191
    if (row < 7168) {
        int t = row / 112, w = row % 112;
        size_t o = (size_t)row * ND + c4 * 4;
        if (w < NW) {
            float s = ws[6144 + t * NW + w];
            float4 v = *(const float4*)&txtK[((size_t)t * NW + w) * ND + c4 * 4];
            v.x *= s; v.y *= s; v.z *= s; v.w *= s;
            split_store(v, &khi[o], &klo[o]);
        } else {
            ushort4 z; z.x = z.y = z.z = z.w = 0;
            *(ushort4*)&khi[o] = z; *(ushort4*)&klo[o] = z;
        }
    } else if (row < 13312) {
        int q = row - 7168;
        float s = ws[q];
        float4 v = *(const float4*)&imgQ[(size_t)q * ND + c4 * 4];
        v.x *= s; v.y *= s; v.z *= s; v.w *= s;
        size_t o = (size_t)q * ND + c4 * 4;
        split_store(v, &qhi[o], &qlo[o]);
    } else if (row < 20480) {
        int rr = row - 13312;
        int t = rr / 112, w = rr % 112;
        size_t o = (size_t)rr * ND + c4 * 4;
        ushort4 u; u.x = u.y = u.z = u.w = 0;
        if (w < NW) {
            float4 v = *(const float4*)&txtV[((size_t)t * NW + w) * ND + c4 * 4];
            u.x = f2bf(v.x); u.y = f2bf(v.y); u.z = f2bf(v.z); u.w = f2bf(v.w);
        }
        *(ushort4*)&tvb[o] = u;
    } else {
        int rr = row - 20480;
        size_t o = (size_t)rr * ND + c4 * 4;
        float4 v = *(const float4*)&imgV[(size_t)rr * ND + c4 * 4];
        ushort4 u; u.x = f2bf(v.x); u.y = f2bf(v.y); u.z = f2bf(v.z); u.w = f2bf(v.w);
        *(ushort4*)&ivb[o] = u;
    }
}

// M[t] = TVB @ TVB^T (112x112, k=768) -> bf16 hi/lo [112][128] (k-pad zero)
__global__ void nafs_gram_m(const ushortt* __restrict__ tvb,
                            ushortt* __restrict__ mh, ushortt* __restrict__ ml) {
    const int t = blockIdx.x;
    const int tid = threadIdx.x, wv = tid >> 6, lane = tid & 63;
    const int quad = lane >> 4, l15 = lane & 15;
    const ushortt* base = tvb + (size_t)t * 112 * ND;
    ushortt* mhB = mh + (size_t)t * 112 * 128;
    ushortt* mlB = ml + (size_t)t * 112 * 128;
#pragma unroll
    for (int a = 0; a < 2; ++a) {
        int m = wv + 4 * a;
        if (m < 7) {
            f32x4 c[7];
#pragma unroll
            for (int n = 0; n < 7; ++n) c[n] = (f32x4){0.f, 0.f, 0.f, 0.f};
            for (int dc = 0; dc < ND; dc += 32) {
                short8 av = *(const short8*)&base[(size_t)(m * 16 + l15) * ND + dc + quad * 8];
#pragma unroll
                for (int n = 0; n < 7; ++n) {
                    short8 bv = *(const short8*)&base[(size_t)(n * 16 + l15) * ND + dc + quad * 8];
                    c[n] = __builtin_amdgcn_mfma_f32_16x16x32_bf16(av, bv, c[n], 0, 0, 0);
                }
            }
#pragma unroll
            for (int n = 0; n < 7; ++n)
#pragma unroll
                for (int reg = 0; reg < 4; ++reg) {
                    int wr = m * 16 + quad * 4 + reg;
                    int wc = n * 16 + l15;
                    float v = c[n][reg];
                    ushortt h = f2bf(v);
                    mhB[wr * 128 + wc] = h;
                    mlB[wr * 128 + wc] = f2bf(v - bf2f(h));
                }
        }
    }
    for (int idx = tid; idx < 112 * 16; idx += 256) {
        int a = idx >> 4, b2 = 112 + (idx & 15);
        mhB[a * 128 + b2] = 0; mlB[a * 128 + b2] = 0;
    }
}

// H[i] = IVB @ IVB^T (48x48, k=768) -> bf16 hi/lo [48][64] (k-pad zero)
__global__ void nafs_gram_h(const ushortt* __restrict__ ivb,
                            ushortt* __restrict__ hh, ushortt* __restrict__ hl) {
    const int i = blockIdx.x;
    const int tid = threadIdx.x, wv = tid >> 6, lane = tid & 63;
    const int quad = lane >> 4, l15 = lane & 15;
    const ushortt* base = ivb + (size_t)i * NR * ND;
    ushortt* hhB = hh + (size_t)i * 48 * 64;
    ushortt* hlB = hl + (size_t)i * 48 * 64;
    if (wv < 3) {
        int m = wv;
        f32x4 c[3];
#pragma unroll
        for (int n = 0; n < 3; ++n) c[n] = (f32x4){0.f, 0.f, 0.f, 0.f};
        for (int dc = 0; dc < ND; dc += 32) {
            short8 av = *(const short8*)&base[(size_t)(m * 16 + l15) * ND + dc + quad * 8];
#pragma unroll
            for (int n = 0; n < 3; ++n) {
                short8 bv = *(const short8*)&base[(size_t)(n * 16 + l15) * ND + dc + quad * 8];
                c[n] = __builtin_amdgcn_mfma_f32_16x16x32_bf16(av, bv, c[n], 0, 0, 0);
            }
        }
#pragma unroll
        for (int n = 0; n < 3; ++n)
#pragma unroll
            for (int reg = 0; reg < 4; ++reg) {
                int rr = m * 16 + quad * 4 + reg;
                int rc = n * 16 + l15;
                float v = c[n][reg];
                ushortt h = f2bf(v);
                hhB[rr * 64 + rc] = h;
                hlB[rr * 64 + rc] = f2bf(v - bf2f(h));
            }
    }
    for (int idx = tid; idx < 48 * 16; idx += 256) {
        int a = idx >> 4, b2 = 48 + (idx & 15);
        hhB[a * 64 + b2] = 0; hlB[a * 64 + b2] = 0;
    }
}

// ======================= fused kernel (fast path) ========================
__global__ __launch_bounds__(256, 3)
void nafs_fused3(const int*  __restrict__ tlen,
                 const float* __restrict__ ws,
                 const ushortt* __restrict__ khi, const ushortt* __restrict__ klo,
                 const ushortt* __restrict__ qhi, const ushortt* __restrict__ qlo,
                 const ushortt* __restrict__ tvb, const ushortt* __restrict__ ivb,
                 const ushortt* __restrict__ mh, const ushortt* __restrict__ ml,
                 const ushortt* __restrict__ hh, const ushortt* __restrict__ hl,
                 float* __restrict__ out) {
    __shared__ __align__(16) float   aT[112 * 49];      // leaky(sim) fp32
    __shared__ __align__(16) ushortt shATT[48 * 128];   // attn bf16, XOR-swizzled
    __shared__ __align__(16) ushortt shATT2[112 * 64];  // attn2 bf16, XOR-swizzled
    __shared__ float sInvW[NW], sInv2[NR], sCos1[NR], sCos2[112];
    __shared__ float sSS1[NR], sDD1[NR], sSS2[112], sDD2[112];

    const int tid  = threadIdx.x;
    const int wv   = tid >> 6;
    const int lane = tid & 63;
    const int quad = lane >> 4;
    const int l15  = lane & 15;
    const int key  = l15 & 7;
    const int b    = blockIdx.x;
    const int g    = b >> 10;
    const int s_   = b & 1023;
    const int t    = ((g & 1) << 5) | (s_ & 31);
    const int i    = ((g >> 1) << 5) | (s_ >> 5);
    const int L    = tlen[t];
    const float Lf = (float)L;

    const float* __restrict__ nVi = ws + 12544;
    const float* __restrict__ nVt = ws + 18688;

    if (tid < NR) { sSS1[tid] = 0.f; sDD1[tid] = 0.f; }

    // ---------------- Phase 1: sim via 3-pass split bf16 MFMA ------------
    const int m0  = wv, m1 = wv + 4;
    const int m1c = (m1 == 7) ? 6 : m1;    // wave3 loads dup tile-6 (discarded)
    const ushortt* pK0h = khi + ((size_t)t * 112 + m0 * 16 + l15) * ND + quad * 8;
    const ushortt* pK0l = klo + ((size_t)t * 112 + m0 * 16 + l15) * ND + quad * 8;
    const ushortt* pK1h = khi + ((size_t)t * 112 + m1c * 16 + l15) * ND + quad * 8;
    const ushortt* pK1l = klo + ((size_t)t * 112 + m1c * 16 + l15) * ND + quad * 8;
    const ushortt* pQh  = qhi + ((size_t)i * NR + l15) * ND + quad * 8;
    const ushortt* pQl  = qlo + ((size_t)i * NR + l15) * ND + quad * 8;

    f32x4 acc[2][3];
#pragma unroll
    for (int a = 0; a < 2; ++a)
#pragma unroll
        for (int n = 0; n < 3; ++n) acc[a][n] = (f32x4){0.f, 0.f, 0.f, 0.f};

    {
        short8 cA0h, cA0l, cA1h, cA1l, cB0h, cB0l, cB1h, cB1l, cB2h, cB2l;
        cA0h = *(const short8*)(pK0h); cA0l = *(const short8*)(pK0l);
        cA1h = *(const short8*)(pK1h); cA1l = *(const short8*)(pK1l);
        cB0h = *(const short8*)(pQh);            cB0l = *(const short8*)(pQl);
        cB1h = *(const short8*)(pQh + 16 * ND);  cB1l = *(const short8*)(pQl + 16 * ND);
        cB2h = *(const short8*)(pQh + 32 * ND);  cB2l = *(const short8*)(pQl + 32 * ND);
        for (int dc = 0; dc < ND; dc += 32) {
            short8 nA0h, nA0l, nA1h, nA1l, nB0h, nB0l, nB1h, nB1l, nB2h, nB2l;
            int dn = dc + 32;
            if (dn < ND) {
                nA0h = *(const short8*)(pK0h + dn); nA0l = *(const short8*)(pK0l + dn);
                nA1h = *(const short8*)(pK1h + dn); nA1l = *(const short8*)(pK1l + dn);
                nB0h = *(const short8*)(pQh + dn);           nB0l = *(const short8*)(pQl + dn);
                nB1h = *(const short8*)(pQh + 16 * ND + dn); nB1l = *(const short8*)(pQl + 16 * ND + dn);
                nB2h = *(const short8*)(pQh + 32 * ND + dn); nB2l = *(const short8*)(pQl + 32 * ND + dn);
            }
            acc[0][0] = __builtin_amdgcn_mfma_f32_16x16x32_bf16(cA0h, cB0h, acc[0][0], 0, 0, 0);
            acc[0][0] = __builtin_amdgcn_mfma_f32_16x16x32_bf16(cA0h, cB0l, acc[0][0], 0, 0, 0);
            acc[0][0] = __builtin_amdgcn_mfma_f32_16x16x32_bf16(cA0l, cB0h, acc[0][0], 0, 0, 0);
            acc[0][1] = __builtin_amdgcn_mfma_f32_16x16x32_bf16(cA0h, cB1h, acc[0][1], 0, 0, 0);
            acc[0][1] = __builtin_amdgcn_mfma_f32_16x16x32_bf16(cA0h, cB1l, acc[0][1], 0, 0, 0);
            acc[0][1] = __builtin_amdgcn_mfma_f32_16x16x32_bf16(cA0l, cB1h, acc[0][1], 0, 0, 0);
            acc[0][2] = __builtin_amdgcn_mfma_f32_16x16x32_bf16(cA0h, cB2h, acc[0][2], 0, 0, 0);
            acc[0][2] = __builtin_amdgcn_mfma_f32_16x16x32_bf16(cA0h, cB2l, acc[0][2], 0, 0, 0);
            acc[0][2] = __builtin_amdgcn_mfma_f32_16x16x32_bf16(cA0l, cB2h, acc[0][2], 0, 0, 0);
            acc[1][0] = __builtin_amdgcn_mfma_f32_16x16x32_bf16(cA1h, cB0h, acc[1][0], 0, 0, 0);
            acc[1][0] = __builtin_amdgcn_mfma_f32_16x16x32_bf16(cA1h, cB0l, acc[1][0], 0, 0, 0);
            acc[1][0] = __builtin_amdgcn_mfma_f32_16x16x32_bf16(cA1l, cB0h, acc[1][0], 0, 0, 0);
            acc[1][1] = __builtin_amdgcn_mfma_f32_16x16x32_bf16(cA1h, cB1h, acc[1][1], 0, 0, 0);
            acc[1][1] = __builtin_amdgcn_mfma_f32_16x16x32_bf16(cA1h, cB1l, acc[1][1], 0, 0, 0);
            acc[1][1] = __builtin_amdgcn_mfma_f32_16x16x32_bf16(cA1l, cB1h, acc[1][1], 0, 0, 0);
            acc[1][2] = __builtin_amdgcn_mfma_f32_16x16x32_bf16(cA1h, cB2h, acc[1][2], 0, 0, 0);
            acc[1][2] = __builtin_amdgcn_mfma_f32_16x16x32_bf16(cA1h, cB2l, acc[1][2], 0, 0, 0);
            acc[1][2] = __builtin_amdgcn_mfma_f32_16x16x32_bf16(cA1l, cB2h, acc[1][2], 0, 0, 0);
            if (dn < ND) {
                cA0h = nA0h; cA0l = nA0l; cA1h = nA1h; cA1l = nA1l;
                cB0h = nB0h; cB0l = nB0l; cB1h = nB1h; cB1l = nB1l; cB2h = nB2h; cB2l = nB2l;
            }
        }
    }
#pragma unroll
    for (int a = 0; a < 2; ++a) {
        int m = (a == 0) ? m0 : m1;
        if (m < 7) {
#pragma unroll
            for (int n = 0; n < 3; ++n)
#pragma unroll
                for (int reg = 0; reg < 4; ++reg) {
                    float s = acc[a][n][reg];
                    aT[(m * 16 + quad * 4 + reg) * 49 + n * 16 + l15] = (s > 0.f) ? s : 0.1f * s;
                }
        }
    }
    __syncthreads();

    // ------- Phase 2: norms + attentions (thread-serial, no shuffles) ----
    if (tid < NW) {
        const float* row = &aT[tid * 49];
        float ss = 0.f;
#pragma unroll 8
        for (int r = 0; r < NR; ++r) { float v = row[r]; ss += v * v; }
        sInvW[tid] = 1.0f / (sqrtf(ss) + EPS);
    } else if (tid >= 128 && tid < 128 + NR) {
        int r = tid - 128;
        float ss = 0.f;
        for (int w = 0; w < L; ++w) { float v = aT[w * 49 + r]; ss += v * v; }
        sInv2[r] = 1.0f / (sqrtf(ss) + EPS);
    }
    __syncthreads();

    if (tid < 112) {
        // branch-2 row w: softmax over r (no max-sub: |x|<=20), sharpen, write bf16
        const int w = tid;
        const int key2 = w & 7;
        if (w < L) {
            const float* row = &aT[w * 49];
            float se = 0.f;
#pragma unroll 8
            for (int r = 0; r < NR; ++r) se += __expf(row[r] * sInv2[r] * LAMB);
            float inv = 1.0f / se;
            float S1 = 0.f;
#pragma unroll 8
            for (int r = 0; r < NR; ++r) S1 += __expf(row[r] * sInv2[r] * LAMB) * inv;
            float S2 = 0.f;
#pragma unroll 8
            for (int r = 0; r < NR; ++r) {
                float p = __expf(row[r] * sInv2[r] * LAMB) * inv;
                S2 += ((p * 48.0f - S1) > 0.f) ? p : 0.f;
            }
            float iS2 = 1.0f / ((S2 > 0.f) ? S2 : 1.0f);
#pragma unroll
            for (int blk = 0; blk < 8; ++blk) {
                ushortt v8[8];
#pragma unroll
                for (int j = 0; j < 8; ++j) {
                    int r = blk * 8 + j;
                    float val = 0.f;
                    if (r < NR) {
                        float p = __expf(row[r] * sInv2[r] * LAMB) * inv;
                        float tm = ((p * 48.0f - S1) > 0.f) ? p : 0.f;
                        val = tm * iS2;
                    }
                    v8[j] = f2bf(val);
                }
                *(short8*)&shATT2[w * 64 + ((blk ^ key2) << 3)] = *(short8*)v8;
            }
        } else {
            short8 z = (short8){0,0,0,0,0,0,0,0};
#pragma unroll
            for (int blk = 0; blk < 8; ++blk)
                *(short8*)&shATT2[w * 64 + ((blk ^ key2) << 3)] = z;
        }
    } else if (tid >= 128 && tid < 128 + NR) {
        // branch-1 row r: softmax over w<L, sharpen, write bf16
        const int r = tid - 128;
        const int key1 = r & 7;
        float se = 0.f;
        for (int w = 0; w < L; ++w) se += __expf(aT[w * 49 + r] * sInvW[w] * LAMB);
        float inv = 1.0f / se;
        float S1 = 0.f;
        for (int w = 0; w < L; ++w) S1 += __expf(aT[w * 49 + r] * sInvW[w] * LAMB) * inv;
        float S2 = 0.f;
        for (int w = 0; w < L; ++w) {
            float p = __expf(aT[w * 49 + r] * sInvW[w] * LAMB) * inv;
            S2 += ((p * Lf - S1) > 0.f) ? p : 0.f;
        }
        float iS2 = 1.0f / ((S2 > 0.f) ? S2 : 1.0f);
        for (int blk = 0; blk < 16; ++blk) {
            ushortt v8[8];
#pragma unroll
            for (int j = 0; j < 8; ++j) {
                int w = blk * 8 + j;
                float val = 0.f;
                if (w < L) {
                    float p = __expf(aT[w * 49 + r] * sInvW[w] * LAMB) * inv;
                    float tm = ((p * Lf - S1) > 0.f) ? p : 0.f;
                    val = tm * iS2;
                }
                v8[j] = f2bf(val);
            }
            *(short8*)&shATT[r * 128 + ((blk ^ key1) << 3)] = *(short8*)v8;
        }
    }
    __syncthreads();

    // ---------------- G-GEMM: G = TVB @ IVB^T (112x48, k=768) ------------
    f32x4 gf[2][3];
#pragma unroll
    for (int a = 0; a < 2; ++a)
#pragma unroll
        for (int n = 0; n < 3; ++n) gf[a][n] = (f32x4){0.f, 0.f, 0.f, 0.f};
    {
        const ushortt* pA0 = tvb + ((size_t)t * 112 + m0 * 16 + l15) * ND + quad * 8;
        const ushortt* pA1 = tvb + ((size_t)t * 112 + m1c * 16 + l15) * ND + quad * 8;
        const ushortt* pB  = ivb + ((size_t)i * NR + l15) * ND + quad * 8;
        short8 cA0 = *(const short8*)(pA0);
        short8 cA1 = *(const short8*)(pA1);
        short8 cB0 = *(const short8*)(pB);
        short8 cB1 = *(const short8*)(pB + 16 * ND);
        short8 cB2 = *(const short8*)(pB + 32 * ND);
        for (int dc = 0; dc < ND; dc += 32) {
            short8 nA0, nA1, nB0, nB1, nB2;
            int dn = dc + 32;
            if (dn < ND) {
                nA0 = *(const short8*)(pA0 + dn);
                nA1 = *(const short8*)(pA1 + dn);
                nB0 = *(const short8*)(pB + dn);
                nB1 = *(const short8*)(pB + 16 * ND + dn);
                nB2 = *(const short8*)(pB + 32 * ND + dn);
            }
            gf[0][0] = __builtin_amdgcn_mfma_f32_16x16x32_bf16(cA0, cB0, gf[0][0], 0, 0, 0);
            gf[0][1] = __builtin_amdgcn_mfma_f32_16x16x32_bf16(cA0, cB1, gf[0][1], 0, 0, 0);
            gf[0][2] = __builtin_amdgcn_mfma_f32_16x16x32_bf16(cA0, cB2, gf[0][2], 0, 0, 0);
            gf[1][0] = __builtin_amdgcn_mfma_f32_16x16x32_bf16(cA1, cB0, gf[1][0], 0, 0, 0);
            gf[1][1] = __builtin_amdgcn_mfma_f32_16x16x32_bf16(cA1, cB1, gf[1][1], 0, 0, 0);
            gf[1][2] = __builtin_amdgcn_mfma_f32_16x16x32_bf16(cA1, cB2, gf[1][2], 0, 0, 0);
            if (dn < ND) { cA0 = nA0; cA1 = nA1; cB0 = nB0; cB1 = nB1; cB2 = nB2; }
        }
    }
    // ---- G epilogue: dd2 (direct), dd1 (atomic) ----
    {
        float pd1[3] = {0.f, 0.f, 0.f};
#pragma unroll
        for (int a = 0; a < 2; ++a) {
            int m = wv + 4 * a;
            if (m < 7) {
#pragma unroll
                for (int reg = 0; reg < 4; ++reg) {
                    int w = m * 16 + quad * 4 + reg;
                    float p2 = 0.f;
#pragma unroll
                    for (int n = 0; n < 3; ++n) {
                        int r = n * 16 + l15;
                        float gv = gf[a][n][reg];
                        p2 = fmaf(gv, bf2f(shATT2[swzATT2(w, r)]), p2);
                        pd1[n] = fmaf(gv, bf2f(shATT[swzATT(r, w)]), pd1[n]);
                    }
                    p2 += __shfl_xor(p2, 1, 64); p2 += __shfl_xor(p2, 2, 64);
                    p2 += __shfl_xor(p2, 4, 64); p2 += __shfl_xor(p2, 8, 64);
                    if (l15 == 0) sDD2[w] = p2;
                }
            }
        }
#pragma unroll
        for (int n = 0; n < 3; ++n) {
            float p = pd1[n];
            p += __shfl_xor(p, 16, 64); p += __shfl_xor(p, 32, 64);
            if (quad == 0) atomicAdd(&sDD1[n * 16 + l15], p);
        }
    }

    // ---------------- Y-GEMM: Y = attn @ M^T, ss1 ------------------------
    {
        short8 af[3][4];
#pragma unroll
        for (int mt = 0; mt < 3; ++mt)
#pragma unroll
            for (int ks = 0; ks < 4; ++ks)
                af[mt][ks] = *(const short8*)&shATT[(mt * 16 + l15) * 128 + (((ks * 4 + quad) ^ key) << 3)];
        float ps[3][4];
#pragma unroll
        for (int mt = 0; mt < 3; ++mt)
#pragma unroll
            for (int reg = 0; reg < 4; ++reg) ps[mt][reg] = 0.f;
#pragma unroll
        for (int p = 0; p < 2; ++p) {
            int nt = wv + 4 * p;
            if (nt < 7) {
                const ushortt* pMh = mh + ((size_t)t * 112 + nt * 16 + l15) * 128 + quad * 8;
                const ushortt* pMl = ml + ((size_t)t * 112 + nt * 16 + l15) * 128 + quad * 8;
                short8 bh[4], bl[4];
#pragma unroll
                for (int ks = 0; ks < 4; ++ks) {
                    bh[ks] = *(const short8*)&pMh[ks * 32];
                    bl[ks] = *(const short8*)&pMl[ks * 32];
                }
                f32x4 y[3];
#pragma unroll
                for (int mt = 0; mt < 3; ++mt) y[mt] = (f32x4){0.f, 0.f, 0.f, 0.f};
#pragma unroll
                for (int mt = 0; mt < 3; ++mt)
#pragma unroll
                    for (int ks = 0; ks < 4; ++ks) {
                        y[mt] = __builtin_amdgcn_mfma_f32_16x16x32_bf16(af[mt][ks], bh[ks], y[mt], 0, 0, 0);
                        y[mt] = __builtin_amdgcn_mfma_f32_16x16x32_bf16(af[mt][ks], bl[ks], y[mt], 0, 0, 0);
                    }
                int wc = nt * 16 + l15;
#pragma unroll
                for (int mt = 0; mt < 3; ++mt)
#pragma unroll
                    for (int reg = 0; reg < 4; ++reg) {
                        int r = mt * 16 + quad * 4 + reg;
                        ps[mt][reg] = fmaf(y[mt][reg], bf2f(shATT[swzATT(r, wc)]), ps[mt][reg]);
                    }
            }
        }
#pragma unroll
        for (int mt = 0; mt < 3; ++mt)
#pragma unroll
            for (int reg = 0; reg < 4; ++reg) {
                float p = ps[mt][reg];
                p += __shfl_xor(p, 1, 64); p += __shfl_xor(p, 2, 64);
                p += __shfl_xor(p, 4, 64); p += __shfl_xor(p, 8, 64);
                if (l15 == 0) atomicAdd(&sSS1[mt * 16 + quad * 4 + reg], p);
            }
    }

    // ---------------- Z-GEMM: Z = attn2 @ H^T, ss2 -----------------------
    {
        short8 zbh[3][2], zbl[3][2];
#pragma unroll
        for (int n = 0; n < 3; ++n) {
            const ushortt* pHh = hh + ((size_t)i * NR + n * 16 + l15) * 64 + quad * 8;
            const ushortt* pHl = hl + ((size_t)i * NR + n * 16 + l15) * 64 + quad * 8;
#pragma unroll
            for (int ks = 0; ks < 2; ++ks) {
                zbh[n][ks] = *(const short8*)&pHh[ks * 32];
                zbl[n][ks] = *(const short8*)&pHl[ks * 32];
            }
        }
#pragma unroll
        for (int a = 0; a < 2; ++a) {
            int m = wv + 4 * a;
            if (m < 7) {
                f32x4 z[3];
#pragma unroll
                for (int n = 0; n < 3; ++n) z[n] = (f32x4){0.f, 0.f, 0.f, 0.f};
#pragma unroll
                for (int ks = 0; ks < 2; ++ks) {
                    short8 a2f = *(const short8*)&shATT2[(m * 16 + l15) * 64 + (((ks * 4 + quad) ^ key) << 3)];
#pragma unroll
                    for (int n = 0; n < 3; ++n) {
                        z[n] = __builtin_amdgcn_mfma_f32_16x16x32_bf16(a2f, zbh[n][ks], z[n], 0, 0, 0);
                        z[n] = __builtin_amdgcn_mfma_f32_16x16x32_bf16(a2f, zbl[n][ks], z[n], 0, 0, 0);
                    }
                }
#pragma unroll
                for (int reg = 0; reg < 4; ++reg) {
                    int w = m * 16 + quad * 4 + reg;
                    float p = 0.f;
#pragma unroll
                    for (int n = 0; n < 3; ++n)
                        p = fmaf(z[n][reg], bf2f(shATT2[swzATT2(w, n * 16 + l15)]), p);
                    p += __shfl_xor(p, 1, 64); p += __shfl_xor(p, 2, 64);
                    p += __shfl_xor(p, 4, 64); p += __shfl_xor(p, 8, 64);
                    if (l15 == 0) sSS2[w] = p;
                }
            }
        }
    }
    __syncthreads();

    // ---------------- cosine epilogue + output ---------------------------
    if (tid < NR) {
        float s = fmaxf(sSS1[tid], 0.f), d = sDD1[tid];
        float nu  = sqrtf(s);
        float num = d / (nu + EPS);
        float den = fmaxf(nVi[i * NR + tid] * (nu / (nu + EPS)), EPS);
        sCos1[tid] = num / den;
    } else if (tid >= 64 && tid < 176) {
        int w = tid - 64;
        if (w < L) {
            float s = fmaxf(sSS2[w], 0.f), d = sDD2[w];
            float nu  = sqrtf(s);
            float num = d / (nu + EPS);
            float den = fmaxf(nVt[t * NW + w] * (nu / (nu + EPS)), EPS);
            sCos2[w] = num / den;
        }
    }
    __syncthreads();
    if (tid == 0) {
        float s = 0.f;
        for (int r = 0; r < NR; ++r) s += sCos1[r];
        out[i * NT + t] = s * (1.0f / 48.0f);
    } else if (tid == 64) {
        float s = 0.f;
        for (int w = 0; w < L; ++w) s += sCos2[w];
        out[NI * NT + i * NT + t] = s / Lf;
    }
}

// ======================= fallback (ws too small) =========================
#define A_KH   0
#define A_KL   4480
#define A_QH   8960
#define A_QL   10880
#define A_ATT  0
#define A_ATT2 6528
#define SHA_SZ 14592
#define B1_TVT 3200
#define B2_IVT 6656
#define SHB_SZ 4900

__global__ __launch_bounds__(256, 3)
void nafs_fused_fb(const float* __restrict__ imgQ,
                   const float* __restrict__ imgV,
                   const float* __restrict__ txtK,
                   const float* __restrict__ txtV,
                   const int*  __restrict__ tlen,
                   const float* __restrict__ ws,
                   float* __restrict__ out) {
    __shared__ ushortt shA[SHA_SZ];
    __shared__ float shB[SHB_SZ];
    __shared__ float sKs[NW], sQs[NR], sInvW[NW], sInv2[NR], sCos1[NR], sCos2[112];

    const int tid  = threadIdx.x;
    const int wv   = tid >> 6;
    const int lane = tid & 63;
    const int quad = lane >> 4;
    const int l15  = lane & 15;
    const int b    = blockIdx.x;
    const int t    = b >> 7;
    const int i    = b & 127;
    const int L    = tlen[t];
    const float Lf = (float)L;

    const float* __restrict__ invQ = ws;
    const float* __restrict__ invK = ws + 6144;
    const float* __restrict__ nVi  = ws + 12544;
    const float* __restrict__ nVt  = ws + 18688;

    const float* Kbase  = txtK + (size_t)t * (NW * ND);
    const float* Qbase  = imgQ + (size_t)i * (NR * ND);
    const float* TVbase = txtV + (size_t)t * (NW * ND);
    const float* IVbase = imgV + (size_t)i * (NR * ND);

    if (tid < NW)                  sKs[tid]       = invK[t * NW + tid];
    else if (tid < NW + NR)        sQs[tid - NW]  = invQ[i * NR + (tid - NW)];

    const int mt0 = wv * 2, mt1 = wv * 2 + 1;
    f32x4 acc[2][3];
#pragma unroll
    for (int a = 0; a < 2; ++a)
#pragma unroll
        for (int n = 0; n < 3; ++n) acc[a][n] = (f32x4){0.f, 0.f, 0.f, 0.f};

    for (int dc = 0; dc < ND; dc += 32) {
        __syncthreads();
        for (int idx = tid; idx < 112 * 8; idx += 256) {
            int w = idx >> 3, seg = idx & 7;
            float4 v;
            if (w < NW) {
                v = *(const float4*)(Kbase + (size_t)w * ND + dc + seg * 4);
                float s = sKs[w];
                v.x *= s; v.y *= s; v.z *= s; v.w *= s;
            } else { v.x = v.y = v.z = v.w = 0.f; }
            split_store(v, &shA[A_KH + w * 40 + seg * 4], &shA[A_KL + w * 40 + seg * 4]);
        }
        for (int idx = tid; idx < NR * 8; idx += 256) {
            int r = idx >> 3, seg = idx & 7;
            float4 v = *(const float4*)(Qbase + (size_t)r * ND + dc + seg * 4);
            float s = sQs[r];
            v.x *= s; v.y *= s; v.z *= s; v.w *= s;
            split_store(v, &shA[A_QH + r * 40 + seg * 4], &shA[A_QL + r * 40 + seg * 4]);
        }
        __syncthreads();
        short8 bh[3], bl[3];
#pragma unroll
        for (int n = 0; n < 3; ++n) {
            bh[n] = *(const short8*)&shA[A_QH + (n * 16 + l15) * 40 + quad * 8];
            bl[n] = *(const short8*)&shA[A_QL + (n * 16 + l15) * 40 + quad * 8];
        }
#pragma unroll
        for (int a = 0; a < 2; ++a) {
            int m = (a == 0) ? mt0 : mt1;
            if (m < 7) {
                short8 ah = *(const short8*)&shA[A_KH + (m * 16 + l15) * 40 + quad * 8];
                short8 al = *(const short8*)&shA[A_KL + (m * 16 + l15) * 40 + quad * 8];
#pragma unroll
                for (int n = 0; n < 3; ++n) {
                    acc[a][n] = __builtin_amdgcn_mfma_f32_16x16x32_bf16(ah, bh[n], acc[a][n], 0, 0, 0);
                    acc[a][n] = __builtin_amdgcn_mfma_f32_16x16x32_bf16(ah, bl[n], acc[a][n], 0, 0, 0);
                    acc[a][n] = __builtin_amdgcn_mfma_f32_16x16x32_bf16(al, bh[n], acc[a][n], 0, 0, 0);
                }
            }
        }
    }
    __syncthreads();
#pragma unroll
    for (int a = 0; a < 2; ++a) {
        int m = (a == 0) ? mt0 : mt1;
        if (m < 7) {
#pragma unroll
            for (int n = 0; n < 3; ++n)
#pragma unroll
                for (int reg = 0; reg < 4; ++reg) {
                    int w = m * 16 + quad * 4 + reg;
                    if (w < NW) {
                        float s = acc[a][n][reg];
                        shB[w * 49 + n * 16 + l15] = (s > 0.f) ? s : 0.1f * s;
                    }
                }
        }
    }
    __syncthreads();

    if (tid < NW) {
        float ssum = 0.f;
#pragma unroll 8
        for (int r = 0; r < NR; ++r) { float v = shB[tid * 49 + r]; ssum += v * v; }
        sInvW[tid] = 1.0f / (sqrtf(ssum) + EPS);
    } else if (tid >= 128 && tid < 128 + NR) {
        int r = tid - 128;
        float ssum = 0.f;
        for (int w = 0; w < L; ++w) { float v = shB[w * 49 + r]; ssum += v * v; }
        sInv2[r] = 1.0f / (sqrtf(ssum) + EPS);
    }
    __syncthreads();

    for (int r = wv; r < NR; r += 4) {
        int w1 = lane, w2 = lane + 64;
        int v1ok = (w1 < L), v2ok = (w2 < L);
        float v1 = v1ok ? shB[w1 * 49 + r] * sInvW[w1] * LAMB : -1e30f;
        float v2 = v2ok ? shB[w2 * 49 + r] * sInvW[w2] * LAMB : -1e30f;
        float m  = wredmax(fmaxf(v1, v2));
        float e1 = v1ok ? expf(v1 - m) : 0.f;
        float e2 = v2ok ? expf(v2 - m) : 0.f;
        float inv = 1.0f / wredsum(e1 + e2);
        float p1 = e1 * inv, p2 = e2 * inv;
        float S1 = wredsum(p1 + p2);
        float t1 = ((p1 * Lf - S1) > 0.f) ? p1 : 0.f;
        float t2 = ((p2 * Lf - S1) > 0.f) ? p2 : 0.f;
        float S2 = wredsum(t1 + t2);
        float iS2 = 1.0f / ((S2 > 0.f) ? S2 : 1.0f);
        shA[A_ATT + r * 136 + w1] = f2bf(t1 * iS2);
        shA[A_ATT + r * 136 + w2] = f2bf(t2 * iS2);
    }
    for (int w = wv; w < L; w += 4) {
        int rok = (lane < NR);
        float v = rok ? shB[w * 49 + lane] * sInv2[lane] * LAMB : -1e30f;
        float m = wredmax(v);
        float e = rok ? expf(v - m) : 0.f;
        float inv = 1.0f / wredsum(e);
        float p = e * inv;
        float S1 = wredsum(p);
        float tm = ((p * 48.0f - S1) > 0.f) ? p : 0.f;
        float S2 = wredsum(tm);
        float iS2 = 1.0f / ((S2 > 0.f) ? S2 : 1.0f);
        shA[A_ATT2 + w * 72 + lane] = f2bf(tm * iS2);
    }
    for (int w = L + wv; w < 112; w += 4) shA[A_ATT2 + w * 72 + lane] = 0;
    __syncthreads();

    ushortt* shBu = (ushortt*)shB;
    const int kk = (L + 31) >> 5;
    float ss1[4] = {0.f, 0.f, 0.f, 0.f}, dd1[4] = {0.f, 0.f, 0.f, 0.f};
    const int mt = wv;
    const int cgrp = tid >> 5, ccol = tid & 31;

    for (int cc = 0; cc < ND; cc += 32) {
        __syncthreads();
        for (int w = cgrp; w < 128; w += 8) {
            float val = (w < NW) ? TVbase[(size_t)w * ND + cc + ccol] : 0.f;
            shBu[B1_TVT + ccol * 136 + w] = f2bf(val);
        }
        for (int idx = tid; idx < NR * 8; idx += 256) {
            int r = idx >> 3, seg = idx & 7;
            float4 v = *(const float4*)(IVbase + (size_t)r * ND + cc + seg * 4);
            float* p = &shB[r * 33 + seg * 4];
            p[0] = v.x; p[1] = v.y; p[2] = v.z; p[3] = v.w;
        }
        __syncthreads();
        if (mt < 3) {
            f32x4 u[2] = {(f32x4){0.f,0.f,0.f,0.f}, (f32x4){0.f,0.f,0.f,0.f}};
            for (int ks = 0; ks < kk; ++ks) {
                short8 a = *(const short8*)&shA[A_ATT + (mt * 16 + l15) * 136 + ks * 32 + quad * 8];
#pragma unroll
                for (int n = 0; n < 2; ++n) {
                    short8 bb = *(const short8*)&shBu[B1_TVT + (n * 16 + l15) * 136 + ks * 32 + quad * 8];
                    u[n] = __builtin_amdgcn_mfma_f32_16x16x32_bf16(a, bb, u[n], 0, 0, 0);
                }
            }
#pragma unroll
            for (int n = 0; n < 2; ++n)
#pragma unroll
                for (int reg = 0; reg < 4; ++reg) {
                    int r = mt * 16 + quad * 4 + reg;
                    float uu = u[n][reg];
                    ss1[reg] = fmaf(uu, uu, ss1[reg]);
                    dd1[reg] = fmaf(uu, shB[r * 33 + n * 16 + l15], dd1[reg]);
                }
        }
    }
    if (mt < 3) {
#pragma unroll
        for (int reg = 0; reg < 4; ++reg) {
            float s = ss1[reg], d = dd1[reg];
#pragma unroll
            for (int m = 1; m < 16; m <<= 1) { s += __shfl_xor(s, m, 64); d += __shfl_xor(d, m, 64); }
            if (l15 == 0) {
                int r = mt * 16 + quad * 4 + reg;
                float nu  = sqrtf(s);
                float num = d / (nu + EPS);
                float den = fmaxf(nVi[i * NR + r] * (nu / (nu + EPS)), EPS);
                sCos1[r] = num / den;
            }
        }
    }

    const int ntot = (L + 15) >> 4;
    float ss2[2] = {0.f, 0.f}, dd2[2] = {0.f, 0.f};

    for (int cc = 0; cc < ND; cc += 32) {
        __syncthreads();
        for (int idx = tid; idx < NW * 8; idx += 256) {
            int w = idx >> 3, seg = idx & 7;
            float4 v = *(const float4*)(TVbase + (size_t)w * ND + cc + seg * 4);
            float* p = &shB[w * 33 + seg * 4];
            p[0] = v.x; p[1] = v.y; p[2] = v.z; p[3] = v.w;
        }
        for (int r = cgrp; r < 64; r += 8) {
            float val = (r < NR) ? IVbase[(size_t)r * ND + cc + ccol] : 0.f;
            shBu[B2_IVT + ccol * 72 + r] = f2bf(val);
        }
        __syncthreads();
#pragma unroll
        for (int pp = 0; pp < 2; ++pp) {
            int nt = wv + 4 * pp;
            if (nt < ntot) {
                f32x4 u[2] = {(f32x4){0.f,0.f,0.f,0.f}, (f32x4){0.f,0.f,0.f,0.f}};
#pragma unroll
                for (int ks = 0; ks < 2; ++ks) {
                    short8 bb = *(const short8*)&shA[A_ATT2 + (nt * 16 + l15) * 72 + ks * 32 + quad * 8];
#pragma unroll
                    for (int mm = 0; mm < 2; ++mm) {
                        short8 aa = *(const short8*)&shBu[B2_IVT + (mm * 16 + l15) * 72 + ks * 32 + quad * 8];
                        u[mm] = __builtin_amdgcn_mfma_f32_16x16x32_bf16(aa, bb, u[mm], 0, 0, 0);
                    }
                }
                int w = nt * 16 + l15;
                float tvok = (w < L) ? 1.f : 0.f;
#pragma unroll
                for (int mm = 0; mm < 2; ++mm)
#pragma unroll
                    for (int reg = 0; reg < 4; ++reg) {
                        int c = mm * 16 + quad * 4 + reg;
                        float uu = u[mm][reg];
                        float tv = (w < L) ? shB[w * 33 + c] : 0.f;
                        ss2[pp] = fmaf(uu, uu, ss2[pp]);
                        dd2[pp] = fmaf(uu, tv * tvok, dd2[pp]);
                    }
            }
        }
    }
#pragma unroll
    for (int pp = 0; pp < 2; ++pp) {
        int nt = wv + 4 * pp;
        if (nt < ntot) {
            float s = ss2[pp], d = dd2[pp];
            s += __shfl_xor(s, 16, 64); d += __shfl_xor(d, 16, 64);
            s += __shfl_xor(s, 32, 64); d += __shfl_xor(d, 32, 64);
            if (quad == 0) {
                int w = nt * 16 + l15;
                if (w < L) {
                    float nu  = sqrtf(s);
                    float num = d / (nu + EPS);
                    float den = fmaxf(nVt[t * NW + w] * (nu / (nu + EPS)), EPS);
                    sCos2[w] = num / den;
                }
            }
        }
    }
    __syncthreads();
    if (tid == 0) {
        float s = 0.f;
        for (int r = 0; r < NR; ++r) s += sCos1[r];
        out[i * NT + t] = s * (1.0f / 48.0f);
    } else if (tid == 64) {
        float s = 0.f;
        for (int w = 0; w < L; ++w) s += sCos2[w];
        out[NI * NT + i * NT + t] = s / Lf;
    }
}

extern "C" void kernel_launch(void* const* d_in, const int* in_sizes, int n_in,
                              void* d_out, int out_size, void* d_ws, size_t ws_size,
                              hipStream_t stream) {
    (void)in_sizes; (void)n_in; (void)out_size;
    const float* imgQ = (const float*)d_in[0];
    const float* imgV = (const float*)d_in[1];
    const float* txtK = (const float*)d_in[2];
    const float* txtV = (const float*)d_in[3];
    const int*   tlen = (const int*)d_in[4];
    float* ws  = (float*)d_ws;
    float* out = (float*)d_out;

    hipLaunchKernelGGL(nafs_norms, dim3(6272), dim3(256), 0, stream,
                       imgQ, imgV, txtK, txtV, ws);

    if (ws_size >= WS_NEED) {
        char* base = (char*)d_ws;
        ushortt* khi = (ushortt*)(base + OFF_KHI);
        ushortt* klo = (ushortt*)(base + OFF_KLO);
        ushortt* qhi = (ushortt*)(base + OFF_QHI);
        ushortt* qlo = (ushortt*)(base + OFF_QLO);
        ushortt* tvb = (ushortt*)(base + OFF_TVB);
        ushortt* ivb = (ushortt*)(base + OFF_IVB);
        ushortt* mh  = (ushortt*)(base + OFF_MH);
        ushortt* ml  = (ushortt*)(base + OFF_ML);
        ushortt* hh  = (ushortt*)(base + OFF_HH);
        ushortt* hl  = (ushortt*)(base + OFF_HL);
        hipLaunchKernelGGL(nafs_convert, dim3(26624), dim3(192), 0, stream,
                           txtK, imgQ, txtV, imgV, ws, khi, klo, qhi, qlo, tvb, ivb);
        hipLaunchKernelGGL(nafs_gram_m, dim3(64), dim3(256), 0, stream, tvb, mh, ml);
        hipLaunchKernelGGL(nafs_gram_h, dim3(128), dim3(256), 0, stream, ivb, hh, hl);
        hipLaunchKernelGGL(nafs_fused3, dim3(NT * NI), dim3(256), 0, stream,
                           tlen, ws, khi, klo, qhi, qlo, tvb, ivb, mh, ml, hh, hl, out);
    } else {
        hipLaunchKernelGGL(nafs_fused_fb, dim3(NT * NI), dim3(256), 0, stream,
                           imgQ, imgV, txtK, txtV, tlen, ws, out);
    }
}